// Round 7
// baseline (399.384 us; speedup 1.0000x reference)
//
#include <hip/hip_runtime.h>
#include <hip/hip_bf16.h>
#include <cstdint>

// Problem constants
#define Bk 32
#define Sk 256
#define Wk 32
#define Tk 16
#define Ek 300
#define Hk 128
#define Dk 128
#define NROWS (Bk*Sk)          // 8192
#define GI_N  (3*Hk*2)         // 768

// ---------------- helpers ----------------
__device__ __forceinline__ float fast_sigmoid(float x) {
    return 1.f / (1.f + __expf(-x));
}
__device__ __forceinline__ float fast_tanh(float x) {
    float ax = fabsf(x);
    float e = __expf(2.f * ax);
    float t = 1.f - 2.f / (1.f + e);
    return copysignf(t, x);
}
// LDS-ordering-only barrier (no vmcnt drain).
__device__ __forceinline__ void barrier_lgkm() {
    asm volatile("s_waitcnt lgkmcnt(0)" ::: "memory");
    __builtin_amdgcn_s_barrier();
}
__device__ __forceinline__ void fma44(const float4& a, const float4& b, float (&c)[4][4]) {
    c[0][0]=fmaf(a.x,b.x,c[0][0]); c[0][1]=fmaf(a.x,b.y,c[0][1]); c[0][2]=fmaf(a.x,b.z,c[0][2]); c[0][3]=fmaf(a.x,b.w,c[0][3]);
    c[1][0]=fmaf(a.y,b.x,c[1][0]); c[1][1]=fmaf(a.y,b.y,c[1][1]); c[1][2]=fmaf(a.y,b.z,c[1][2]); c[1][3]=fmaf(a.y,b.w,c[1][3]);
    c[2][0]=fmaf(a.z,b.x,c[2][0]); c[2][1]=fmaf(a.z,b.y,c[2][1]); c[2][2]=fmaf(a.z,b.z,c[2][2]); c[2][3]=fmaf(a.z,b.w,c[2][3]);
    c[3][0]=fmaf(a.w,b.x,c[3][0]); c[3][1]=fmaf(a.w,b.y,c[3][1]); c[3][2]=fmaf(a.w,b.z,c[3][2]); c[3][3]=fmaf(a.w,b.w,c[3][3]);
}

// ---------------- pack kernel ----------------
__global__ __launch_bounds__(256) void pack_kernel(
    const float* __restrict__ Wf, const float* __restrict__ Wb,
    const float* __restrict__ bf, const float* __restrict__ bb,
    const float* __restrict__ W1,
    float* __restrict__ Bgi, float* __restrict__ bias_gi, float* __restrict__ BW1)
{
    int idx = blockIdx.x * 256 + threadIdx.x;
    if (idx < 300 * 768) {
        int k = idx / 768, n = idx % 768;
        Bgi[idx] = (n < 384) ? Wf[n * 300 + k] : Wb[(n - 384) * 300 + k];
    }
    if (idx < 768) bias_gi[idx] = (idx < 384) ? bf[idx] : bb[idx - 384];
    if (idx < 512 * 128) {
        int k = idx >> 7, n = idx & 127;
        BW1[idx] = W1[n * 512 + k];
    }
}

// ---------------- embedding mean ----------------
__global__ __launch_bounds__(256) void embed_mean_kernel(
    const int* __restrict__ wids, const float* __restrict__ table,
    float* __restrict__ sent_emb)
{
    int wv = (blockIdx.x << 2) + (threadIdx.x >> 6);
    int lane = threadIdx.x & 63;
    if (wv >= NROWS) return;
    const int* idp = wids + (size_t)wv * Wk;
    float4 a0 = {0,0,0,0}, a1 = {0,0,0,0};
    #pragma unroll 4
    for (int w = 0; w < Wk; ++w) {
        int id = idp[w];
        const float4* r4 = reinterpret_cast<const float4*>(table + (size_t)id * Ek);
        float4 v0 = r4[lane];
        a0.x += v0.x; a0.y += v0.y; a0.z += v0.z; a0.w += v0.w;
        if (lane < 11) {
            float4 v1 = r4[64 + lane];
            a1.x += v1.x; a1.y += v1.y; a1.z += v1.z; a1.w += v1.w;
        }
    }
    const float sc = 1.f / 32.f;
    float4* o4 = reinterpret_cast<float4*>(sent_emb + (size_t)wv * Ek);
    float4 o0 = {a0.x*sc, a0.y*sc, a0.z*sc, a0.w*sc};
    o4[lane] = o0;
    if (lane < 11) {
        float4 o1 = {a1.x*sc, a1.y*sc, a1.z*sc, a1.w*sc};
        o4[64 + lane] = o1;
    }
}

// ---------------- 64x64 fp32 GEMM (r2 known-good; small/odd shapes) --------
template<bool BIAS, bool RELU>
__global__ __launch_bounds__(256) void gemm_kernel(
    const float* __restrict__ A, const float* __restrict__ B,
    const float* __restrict__ bias, float* __restrict__ C,
    int M, int N, int K)
{
    __shared__ float As[64][68];
    __shared__ float Bs[64][68];
    const int tid = threadIdx.x;
    const int m0 = blockIdx.x * 64;
    const int n0 = blockIdx.y * 64;
    const int tx = tid & 15, ty = tid >> 4;
    const int lr = tid >> 2;
    const int lc = tid & 3;
    float acc[4][4] = {};

    for (int k0 = 0; k0 < K; k0 += 64) {
        #pragma unroll
        for (int i = 0; i < 4; ++i) {
            int kk = lc * 4 + i * 16;
            int gm = m0 + lr;
            int gk = k0 + kk;
            float4 v = {0,0,0,0};
            if (gm < M && gk < K)
                v = *reinterpret_cast<const float4*>(A + (size_t)gm * K + gk);
            As[kk+0][lr] = v.x; As[kk+1][lr] = v.y; As[kk+2][lr] = v.z; As[kk+3][lr] = v.w;
        }
        #pragma unroll
        for (int i = 0; i < 4; ++i) {
            int nn = lc * 4 + i * 16;
            int gk = k0 + lr;
            float4 v = {0,0,0,0};
            if (gk < K)
                v = *reinterpret_cast<const float4*>(B + (size_t)gk * N + n0 + nn);
            *reinterpret_cast<float4*>(&Bs[lr][nn]) = v;
        }
        __syncthreads();
        #pragma unroll 8
        for (int k = 0; k < 64; ++k) {
            float4 av = *reinterpret_cast<const float4*>(&As[k][ty*4]);
            float4 bv = *reinterpret_cast<const float4*>(&Bs[k][tx*4]);
            fma44(av, bv, acc);
        }
        __syncthreads();
    }
    #pragma unroll
    for (int r = 0; r < 4; ++r) {
        int row = m0 + ty * 4 + r;
        if (row < M) {
            float4 v = {acc[r][0], acc[r][1], acc[r][2], acc[r][3]};
            if (BIAS) {
                const float* bp = bias + n0 + tx * 4;
                v.x += bp[0]; v.y += bp[1]; v.z += bp[2]; v.w += bp[3];
            }
            if (RELU) {
                v.x = fmaxf(v.x, 0.f); v.y = fmaxf(v.y, 0.f);
                v.z = fmaxf(v.z, 0.f); v.w = fmaxf(v.w, 0.f);
            }
            *reinterpret_cast<float4*>(C + (size_t)row * N + n0 + tx * 4) = v;
        }
    }
}

// ---------------- 128x64 fp32 GEMM (r7: 3 b128 : 32 FMA inner) ------------
// Tile 128(m) x 64(n), BK=32. 256 threads: tx=tid&15 (n off tx*4),
// ty=tid>>4 (rows ty*8..+7). Per k: 2 b128 A-reads (broadcast over tx;
// ty*32B apart -> distinct banks) + 1 b128 B-read (2-way = free) + 32 FMA.
// Requires M%128==0, N%64==0, K%4==0 (gi: 8192x768x300, SW: 8192x512x256).
// LDS 25.6KB -> ~5 blocks/CU. Grid: (M/128)*(N/64) = 768 / 512 blocks
// (exact multiples of 256 CUs -- r5's gemm128 lost to grid imbalance).
template<bool BIAS>
__global__ __launch_bounds__(256) void gemm_m128n64_kernel(
    const float* __restrict__ A, const float* __restrict__ B,
    const float* __restrict__ bias, float* __restrict__ C,
    int M, int N, int K)
{
    __shared__ float As[32][132];   // transposed: As[k][m]
    __shared__ float Bs[32][68];
    const int tid = threadIdx.x;
    const int m0 = blockIdx.x * 128;
    const int n0 = blockIdx.y * 64;
    const int tx = tid & 15, ty = tid >> 4;
    float acc0[4][4] = {};
    float acc1[4][4] = {};

    const int ar  = tid >> 1;            // A stage row 0..127
    const int ah  = (tid & 1) * 16;      // A stage k-half base
    const int bk_ = tid >> 3;            // B stage k row 0..31
    const int bn  = (tid & 7) * 8;       // B stage n base (2 float4)

    for (int k0 = 0; k0 < K; k0 += 32) {
        // stage A transposed: thread loads 4 float4 of its row, scatters
        #pragma unroll
        for (int i = 0; i < 4; ++i) {
            int kk = ah + i * 4;
            int gk = k0 + kk;
            float4 v = {0,0,0,0};
            if (gk + 4 <= K)
                v = *reinterpret_cast<const float4*>(A + (size_t)(m0 + ar) * K + gk);
            As[kk+0][ar] = v.x; As[kk+1][ar] = v.y; As[kk+2][ar] = v.z; As[kk+3][ar] = v.w;
        }
        // stage B: 2 coalesced float4 per thread
        {
            int gk = k0 + bk_;
            float4 v0 = {0,0,0,0}, v1 = {0,0,0,0};
            if (gk < K) {
                v0 = *reinterpret_cast<const float4*>(B + (size_t)gk * N + n0 + bn);
                v1 = *reinterpret_cast<const float4*>(B + (size_t)gk * N + n0 + bn + 4);
            }
            *reinterpret_cast<float4*>(&Bs[bk_][bn])     = v0;
            *reinterpret_cast<float4*>(&Bs[bk_][bn + 4]) = v1;
        }
        __syncthreads();
        #pragma unroll 8
        for (int k = 0; k < 32; ++k) {
            float4 a0 = *reinterpret_cast<const float4*>(&As[k][ty * 8]);
            float4 a1 = *reinterpret_cast<const float4*>(&As[k][ty * 8 + 4]);
            float4 bv = *reinterpret_cast<const float4*>(&Bs[k][tx * 4]);
            fma44(a0, bv, acc0);
            fma44(a1, bv, acc1);
        }
        __syncthreads();
    }
    float4 bvad = {0,0,0,0};
    if (BIAS) {
        const float* bp = bias + n0 + tx * 4;
        bvad.x = bp[0]; bvad.y = bp[1]; bvad.z = bp[2]; bvad.w = bp[3];
    }
    #pragma unroll
    for (int r = 0; r < 4; ++r) {
        int row = m0 + ty * 8 + r;
        float4 v = {acc0[r][0] + bvad.x, acc0[r][1] + bvad.y,
                    acc0[r][2] + bvad.z, acc0[r][3] + bvad.w};
        *reinterpret_cast<float4*>(C + (size_t)row * N + n0 + tx * 4) = v;
    }
    #pragma unroll
    for (int r = 0; r < 4; ++r) {
        int row = m0 + ty * 8 + 4 + r;
        float4 v = {acc1[r][0] + bvad.x, acc1[r][1] + bvad.y,
                    acc1[r][2] + bvad.z, acc1[r][3] + bvad.w};
        *reinterpret_cast<float4*>(C + (size_t)row * N + n0 + tx * 4) = v;
    }
}

// ---------------- GRU scan (r6: single barrier / step) ----------------
__global__ __launch_bounds__(512, 1) void gru_scan_kernel(
    const float* __restrict__ gi,       // [8192, 768], col = dir*384 + g
    const float* __restrict__ Whh_f, const float* __restrict__ Whh_b,
    const float* __restrict__ bhh_f, const float* __restrict__ bhh_b,
    float* __restrict__ sent_rep,       // [8192, 256], col = dir*128 + j
    float* __restrict__ hT)             // [2][32][128]
{
    const int blk = blockIdx.x;
    const int dir = blk >> 5;
    const int b   = blk & 31;
    const int t = threadIdx.x;
    const int lane = t & 63;
    const int w_id = t >> 6;
    const int q = lane >> 4;          // h segment 0..3
    const int m = lane & 15;
    const int j = w_id * 16 + m;      // hidden index 0..127
    const float* Whh = dir ? Whh_b : Whh_f;
    const float* bhh = dir ? bhh_b : bhh_f;
    __shared__ float hbufA[144];   // 4 segs of 32, padded stride 36
    __shared__ float hbufB[144];

    const float* wr0 = Whh + (size_t)j * 128 + 32 * q;
    const float* wr1 = wr0 + 128 * 128;
    const float* wr2 = wr0 + 256 * 128;
    float4 wA0 = *reinterpret_cast<const float4*>(wr0 +  0);
    float4 wA1 = *reinterpret_cast<const float4*>(wr0 +  4);
    float4 wA2 = *reinterpret_cast<const float4*>(wr0 +  8);
    float4 wA3 = *reinterpret_cast<const float4*>(wr0 + 12);
    float4 wA4 = *reinterpret_cast<const float4*>(wr0 + 16);
    float4 wA5 = *reinterpret_cast<const float4*>(wr0 + 20);
    float4 wA6 = *reinterpret_cast<const float4*>(wr0 + 24);
    float4 wA7 = *reinterpret_cast<const float4*>(wr0 + 28);
    float4 wB0 = *reinterpret_cast<const float4*>(wr1 +  0);
    float4 wB1 = *reinterpret_cast<const float4*>(wr1 +  4);
    float4 wB2 = *reinterpret_cast<const float4*>(wr1 +  8);
    float4 wB3 = *reinterpret_cast<const float4*>(wr1 + 12);
    float4 wB4 = *reinterpret_cast<const float4*>(wr1 + 16);
    float4 wB5 = *reinterpret_cast<const float4*>(wr1 + 20);
    float4 wB6 = *reinterpret_cast<const float4*>(wr1 + 24);
    float4 wB7 = *reinterpret_cast<const float4*>(wr1 + 28);
    float4 wC0 = *reinterpret_cast<const float4*>(wr2 +  0);
    float4 wC1 = *reinterpret_cast<const float4*>(wr2 +  4);
    float4 wC2 = *reinterpret_cast<const float4*>(wr2 +  8);
    float4 wC3 = *reinterpret_cast<const float4*>(wr2 + 12);
    float4 wC4 = *reinterpret_cast<const float4*>(wr2 + 16);
    float4 wC5 = *reinterpret_cast<const float4*>(wr2 + 20);
    float4 wC6 = *reinterpret_cast<const float4*>(wr2 + 24);
    float4 wC7 = *reinterpret_cast<const float4*>(wr2 + 28);
    const float br = bhh[j];
    const float bz = bhh[128 + j];
    const float bn = bhh[256 + j];

    if (t < 144) { hbufA[t] = 0.f; hbufB[t] = 0.f; }

    const int ji = 36 * (j >> 5) + (j & 31);   // padded write index
    const float* gbase = gi + (size_t)(b * Sk) * GI_N + dir * 384 + j;
    float hold = 0.f;
    float gir = 0.f, giz = 0.f, gin_ = 0.f;
    {
        const int s0 = dir ? (Sk - 1) : 0;
        const float* gp = gbase + (size_t)s0 * GI_N;
        gir = gp[0]; giz = gp[128]; gin_ = gp[256];
    }
    __syncthreads();

    #define STEP(RD, WR, SEXPR) { \
        const int s = (SEXPR); \
        const float4* hseg = reinterpret_cast<const float4*>(RD) + 9 * q; \
        float pA = 0.f, pB = 0.f, pC = 0.f; \
        { float4 h4; \
          h4 = hseg[0]; \
          pA=fmaf(wA0.x,h4.x,pA); pA=fmaf(wA0.y,h4.y,pA); pA=fmaf(wA0.z,h4.z,pA); pA=fmaf(wA0.w,h4.w,pA); \
          pB=fmaf(wB0.x,h4.x,pB); pB=fmaf(wB0.y,h4.y,pB); pB=fmaf(wB0.z,h4.z,pB); pB=fmaf(wB0.w,h4.w,pB); \
          pC=fmaf(wC0.x,h4.x,pC); pC=fmaf(wC0.y,h4.y,pC); pC=fmaf(wC0.z,h4.z,pC); pC=fmaf(wC0.w,h4.w,pC); \
          h4 = hseg[1]; \
          pA=fmaf(wA1.x,h4.x,pA); pA=fmaf(wA1.y,h4.y,pA); pA=fmaf(wA1.z,h4.z,pA); pA=fmaf(wA1.w,h4.w,pA); \
          pB=fmaf(wB1.x,h4.x,pB); pB=fmaf(wB1.y,h4.y,pB); pB=fmaf(wB1.z,h4.z,pB); pB=fmaf(wB1.w,h4.w,pB); \
          pC=fmaf(wC1.x,h4.x,pC); pC=fmaf(wC1.y,h4.y,pC); pC=fmaf(wC1.z,h4.z,pC); pC=fmaf(wC1.w,h4.w,pC); \
          h4 = hseg[2]; \
          pA=fmaf(wA2.x,h4.x,pA); pA=fmaf(wA2.y,h4.y,pA); pA=fmaf(wA2.z,h4.z,pA); pA=fmaf(wA2.w,h4.w,pA); \
          pB=fmaf(wB2.x,h4.x,pB); pB=fmaf(wB2.y,h4.y,pB); pB=fmaf(wB2.z,h4.z,pB); pB=fmaf(wB2.w,h4.w,pB); \
          pC=fmaf(wC2.x,h4.x,pC); pC=fmaf(wC2.y,h4.y,pC); pC=fmaf(wC2.z,h4.z,pC); pC=fmaf(wC2.w,h4.w,pC); \
          h4 = hseg[3]; \
          pA=fmaf(wA3.x,h4.x,pA); pA=fmaf(wA3.y,h4.y,pA); pA=fmaf(wA3.z,h4.z,pA); pA=fmaf(wA3.w,h4.w,pA); \
          pB=fmaf(wB3.x,h4.x,pB); pB=fmaf(wB3.y,h4.y,pB); pB=fmaf(wB3.z,h4.z,pB); pB=fmaf(wB3.w,h4.w,pB); \
          pC=fmaf(wC3.x,h4.x,pC); pC=fmaf(wC3.y,h4.y,pC); pC=fmaf(wC3.z,h4.z,pC); pC=fmaf(wC3.w,h4.w,pC); \
          h4 = hseg[4]; \
          pA=fmaf(wA4.x,h4.x,pA); pA=fmaf(wA4.y,h4.y,pA); pA=fmaf(wA4.z,h4.z,pA); pA=fmaf(wA4.w,h4.w,pA); \
          pB=fmaf(wB4.x,h4.x,pB); pB=fmaf(wB4.y,h4.y,pB); pB=fmaf(wB4.z,h4.z,pB); pB=fmaf(wB4.w,h4.w,pB); \
          pC=fmaf(wC4.x,h4.x,pC); pC=fmaf(wC4.y,h4.y,pC); pC=fmaf(wC4.z,h4.z,pC); pC=fmaf(wC4.w,h4.w,pC); \
          h4 = hseg[5]; \
          pA=fmaf(wA5.x,h4.x,pA); pA=fmaf(wA5.y,h4.y,pA); pA=fmaf(wA5.z,h4.z,pA); pA=fmaf(wA5.w,h4.w,pA); \
          pB=fmaf(wB5.x,h4.x,pB); pB=fmaf(wB5.y,h4.y,pB); pB=fmaf(wB5.z,h4.z,pB); pB=fmaf(wB5.w,h4.w,pB); \
          pC=fmaf(wC5.x,h4.x,pC); pC=fmaf(wC5.y,h4.y,pC); pC=fmaf(wC5.z,h4.z,pC); pC=fmaf(wC5.w,h4.w,pC); \
          h4 = hseg[6]; \
          pA=fmaf(wA6.x,h4.x,pA); pA=fmaf(wA6.y,h4.y,pA); pA=fmaf(wA6.z,h4.z,pA); pA=fmaf(wA6.w,h4.w,pA); \
          pB=fmaf(wB6.x,h4.x,pB); pB=fmaf(wB6.y,h4.y,pB); pB=fmaf(wB6.z,h4.z,pB); pB=fmaf(wB6.w,h4.w,pB); \
          pC=fmaf(wC6.x,h4.x,pC); pC=fmaf(wC6.y,h4.y,pC); pC=fmaf(wC6.z,h4.z,pC); pC=fmaf(wC6.w,h4.w,pC); \
          h4 = hseg[7]; \
          pA=fmaf(wA7.x,h4.x,pA); pA=fmaf(wA7.y,h4.y,pA); pA=fmaf(wA7.z,h4.z,pA); pA=fmaf(wA7.w,h4.w,pA); \
          pB=fmaf(wB7.x,h4.x,pB); pB=fmaf(wB7.y,h4.y,pB); pB=fmaf(wB7.z,h4.z,pB); pB=fmaf(wB7.w,h4.w,pB); \
          pC=fmaf(wC7.x,h4.x,pC); pC=fmaf(wC7.y,h4.y,pC); pC=fmaf(wC7.z,h4.z,pC); pC=fmaf(wC7.w,h4.w,pC); } \
        pA += __shfl_xor(pA, 16); pA += __shfl_xor(pA, 32); \
        pB += __shfl_xor(pB, 16); pB += __shfl_xor(pB, 32); \
        pC += __shfl_xor(pC, 16); pC += __shfl_xor(pC, 32); \
        if (q == 0) { \
            float r = fast_sigmoid(gir + pA + br); \
            float z = fast_sigmoid(giz + pB + bz); \
            float n = fast_tanh(gin_ + r * (pC + bn)); \
            hold = (1.f - z) * n + z * hold; \
            (WR)[ji] = hold; \
            sent_rep[(size_t)(b * Sk + s) * 256 + dir * 128 + j] = hold; \
            const int sn = dir ? (s > 0 ? s - 1 : 0) : (s + 1 < Sk ? s + 1 : Sk - 1); \
            const float* gp = gbase + (size_t)sn * GI_N; \
            gir = gp[0]; giz = gp[128]; gin_ = gp[256]; \
        } \
        barrier_lgkm(); \
    }

    for (int step = 0; step < Sk; step += 2) {
        STEP(hbufA, hbufB, dir ? (Sk - 1 - step) : step);
        STEP(hbufB, hbufA, dir ? (Sk - 2 - step) : (step + 1));
    }
    #undef STEP

    if (q == 0) hT[dir * 4096 + b * 128 + j] = hold;
}

// ---------------- prep: doc_vec + topic_mat ----------------
__device__ __forceinline__ float4 sr_load_guard(const float* sr, int b, int sidx, int j4) {
    if (sidx < 0 || sidx >= Sk) { float4 z = {0,0,0,0}; return z; }
    return reinterpret_cast<const float4*>(sr)[(size_t)(b * Sk + sidx) * 64 + j4];
}
__global__ __launch_bounds__(64) void prep_kernel(
    const int* __restrict__ tse, const float* __restrict__ sent_rep,
    const float* __restrict__ hT, float* __restrict__ dvtm)
{
    const int b = blockIdx.x;
    const int t = blockIdx.y;
    const int j4 = threadIdx.x;   // 0..63 (float4 col)
    if (t == 16) {
        int dir = b >> 4;
        int bb = 2 * (b & 15) + (j4 >> 5);
        int jj4 = j4 & 31;
        float4 v = reinterpret_cast<const float4*>(hT)[dir * 1024 + bb * 32 + jj4];
        reinterpret_cast<float4*>(dvtm)[b * 64 + j4] = v;
    } else {
        int st = tse[b * 32 + t * 2];
        int en = tse[b * 32 + t * 2 + 1];
        float4 va, vb;
        if (j4 < 32) {
            va = sr_load_guard(sent_rep, b, en - 1, j4);
            vb = sr_load_guard(sent_rep, b, st - 2, j4);
        } else {
            va = sr_load_guard(sent_rep, b, st - 1, j4);
            vb = sr_load_guard(sent_rep, b, en, j4);
        }
        float4 v = {va.x - vb.x, va.y - vb.y, va.z - vb.z, va.w - vb.w};
        reinterpret_cast<float4*>(dvtm)[(32 + b * 16 + t) * 64 + j4] = v;
    }
}

// ---------------- scores ----------------
__global__ __launch_bounds__(256) void scores_kernel(
    const float* __restrict__ SW,    // [8192,512]
    const float* __restrict__ dptp,  // [544,512]
    const float* __restrict__ vatt,  // [512]
    const int* __restrict__ tse,
    float* __restrict__ dsc, float* __restrict__ tsc)
{
    int row = (blockIdx.x << 2) + (threadIdx.x >> 6);
    int lane = threadIdx.x & 63;
    if (row >= NROWS) return;
    int b = row >> 8, s = row & 255;
    int ti = 0;
    #pragma unroll
    for (int t = 1; t < 16; ++t) ti += (s >= tse[b * 32 + t * 2] - 1) ? 1 : 0;
    const float4* swr = reinterpret_cast<const float4*>(SW + (size_t)row * 512);
    const float4* dpr = reinterpret_cast<const float4*>(dptp + (size_t)b * 512);
    const float4* tpr = reinterpret_cast<const float4*>(dptp + (size_t)(32 + b * 16 + ti) * 512);
    const float4* vv  = reinterpret_cast<const float4*>(vatt);
    float sd = 0.f, st = 0.f;
    #pragma unroll
    for (int q = 0; q < 2; ++q) {
        int i = lane * 2 + q;
        float4 sw = swr[i], dp = dpr[i], tp = tpr[i], v = vv[i];
        sd += fast_tanh(sw.x + dp.x) * v.x + fast_tanh(sw.y + dp.y) * v.y
            + fast_tanh(sw.z + dp.z) * v.z + fast_tanh(sw.w + dp.w) * v.w;
        st += fast_tanh(sw.x + tp.x) * v.x + fast_tanh(sw.y + tp.y) * v.y
            + fast_tanh(sw.z + tp.z) * v.z + fast_tanh(sw.w + tp.w) * v.w;
    }
    #pragma unroll
    for (int off = 32; off; off >>= 1) {
        sd += __shfl_xor(sd, off);
        st += __shfl_xor(st, off);
    }
    if (lane == 0) { dsc[row] = sd; tsc[row] = st; }
}

// ---------------- softmax ----------------
__global__ __launch_bounds__(256) void softmax_kernel(float* __restrict__ dsc, float* __restrict__ tsc)
{
    const int b = blockIdx.x, sidx = threadIdx.x;
    const int lane = sidx & 63, wid = sidx >> 6;
    __shared__ float rd[4], rt[4];
    float d = dsc[b * Sk + sidx];
    float t = tsc[b * Sk + sidx];
    float md = d, mt = t;
    #pragma unroll
    for (int off = 32; off; off >>= 1) {
        md = fmaxf(md, __shfl_xor(md, off));
        mt = fmaxf(mt, __shfl_xor(mt, off));
    }
    if (lane == 0) { rd[wid] = md; rt[wid] = mt; }
    __syncthreads();
    md = fmaxf(fmaxf(rd[0], rd[1]), fmaxf(rd[2], rd[3]));
    mt = fmaxf(fmaxf(rt[0], rt[1]), fmaxf(rt[2], rt[3]));
    float ed = __expf(d - md), et = __expf(t - mt);
    float sd = ed, stt = et;
    #pragma unroll
    for (int off = 32; off; off >>= 1) {
        sd += __shfl_xor(sd, off);
        stt += __shfl_xor(stt, off);
    }
    __syncthreads();
    if (lane == 0) { rd[wid] = sd; rt[wid] = stt; }
    __syncthreads();
    sd = rd[0] + rd[1] + rd[2] + rd[3];
    stt = rt[0] + rt[1] + rt[2] + rt[3];
    dsc[b * Sk + sidx] = ed / sd;
    tsc[b * Sk + sidx] = et / stt;
}

// ---------------- build inp = [sent_rep, context] ----------------
__global__ __launch_bounds__(128) void build_inp_kernel(
    const float* __restrict__ sent_rep, const float* __restrict__ dvtm,
    const float* __restrict__ dw, const float* __restrict__ tw,
    const int* __restrict__ tse, float* __restrict__ inp)
{
    int row = blockIdx.x;
    int b = row >> 8, s = row & 255;
    int f4c = threadIdx.x;   // 0..127
    float4 v;
    if (f4c < 64) {
        v = reinterpret_cast<const float4*>(sent_rep)[(size_t)row * 64 + f4c];
    } else {
        int ti = 0;
        #pragma unroll
        for (int t = 1; t < 16; ++t) ti += (s >= tse[b * 32 + t * 2] - 1) ? 1 : 0;
        float dwv = dw[row], twv = tw[row];
        int j4 = f4c - 64;
        float4 dv = reinterpret_cast<const float4*>(dvtm)[b * 64 + j4];
        float4 tm = reinterpret_cast<const float4*>(dvtm)[(32 + b * 16 + ti) * 64 + j4];
        v.x = dwv * dv.x + twv * tm.x;
        v.y = dwv * dv.y + twv * tm.y;
        v.z = dwv * dv.z + twv * tm.z;
        v.w = dwv * dv.w + twv * tm.w;
    }
    reinterpret_cast<float4*>(inp)[(size_t)row * 128 + f4c] = v;
}

// ---------------- final logits ----------------
__global__ __launch_bounds__(256) void logits_kernel(
    const float* __restrict__ hdd, const float* __restrict__ W2,
    const float* __restrict__ b2, float* __restrict__ out)
{
    int row = (blockIdx.x << 2) + (threadIdx.x >> 6);
    int lane = threadIdx.x & 63;
    if (row >= NROWS) return;
    float acc = hdd[(size_t)row * 128 + lane] * W2[lane]
              + hdd[(size_t)row * 128 + 64 + lane] * W2[64 + lane];
    #pragma unroll
    for (int off = 32; off; off >>= 1) acc += __shfl_xor(acc, off);
    if (lane == 0) out[row] = acc + b2[0];
}

// ---------------- launch ----------------
extern "C" void kernel_launch(void* const* d_in, const int* in_sizes, int n_in,
                              void* d_out, int out_size, void* d_ws, size_t ws_size,
                              hipStream_t stream)
{
    const int*   wids  = (const int*)d_in[0];
    const int*   tse   = (const int*)d_in[1];
    const float* table = (const float*)d_in[2];
    const float* Wihf  = (const float*)d_in[3];
    const float* Whhf  = (const float*)d_in[4];
    const float* bihf  = (const float*)d_in[5];
    const float* bhhf  = (const float*)d_in[6];
    const float* Wihb  = (const float*)d_in[7];
    const float* Whhb  = (const float*)d_in[8];
    const float* bihb  = (const float*)d_in[9];
    const float* bhhb  = (const float*)d_in[10];
    const float* vatt  = (const float*)d_in[11];
    const float* Watt  = (const float*)d_in[12];
    const float* W1    = (const float*)d_in[13];
    const float* b1    = (const float*)d_in[14];
    const float* W2    = (const float*)d_in[15];
    const float* b2    = (const float*)d_in[16];
    float* ws = (float*)d_ws;
    float* out = (float*)d_out;

    float* sent_emb = ws + 0;          // 2,457,600  (dead after gi GEMM)
    float* gi       = ws + 2457600;    // 6,291,456  (dead after scan)
    float* sent_rep = ws + 8749056;    // 2,097,152
    float* hT       = ws + 10846208;   // 8,192
    float* dvtm     = ws + 10854400;   // 139,264 ([544][256])
    float* dptp     = ws + 10993664;   // 278,528 ([544][512])
    float* dsc      = ws + 11272192;   // 8,192
    float* tsc      = ws + 11280384;   // 8,192
    float* Bgi      = ws + 11288576;   // 230,400
    float* bias_gi  = ws + 11518976;   // 768
    float* BW1      = ws + 11519744;   // 65,536  -> end 11,585,280 floats
    float* SW       = ws + 0;          // [8192][512] over sent_emb+gi (dead)
    float* inp      = ws + 4194304;    // [8192][512]
    float* hdd      = ws + 0;          // [8192][128] over SW (dead after scores)

    if (ws_size < (size_t)11585280 * sizeof(float)) return;

    pack_kernel<<<900, 256, 0, stream>>>(Wihf, Wihb, bihf, bihb, W1, Bgi, bias_gi, BW1);
    embed_mean_kernel<<<2048, 256, 0, stream>>>(wids, table, sent_emb);
    gemm_m128n64_kernel<true><<<dim3(64, 12), 256, 0, stream>>>(sent_emb, Bgi, bias_gi, gi, NROWS, 768, 300);
    gru_scan_kernel<<<64, 512, 0, stream>>>(gi, Whhf, Whhb, bhhf, bhhb, sent_rep, hT);
    prep_kernel<<<dim3(32, 17), 64, 0, stream>>>(tse, sent_rep, hT, dvtm);
    gemm_m128n64_kernel<false><<<dim3(64, 8), 256, 0, stream>>>(sent_rep, Watt + 256 * 512, nullptr, SW, NROWS, 512, 256);
    gemm_kernel<false,false><<<dim3(9, 8), 256, 0, stream>>>(dvtm, Watt, nullptr, dptp, 544, 512, 256);
    scores_kernel<<<2048, 256, 0, stream>>>(SW, dptp, vatt, tse, dsc, tsc);
    softmax_kernel<<<32, 256, 0, stream>>>(dsc, tsc);
    build_inp_kernel<<<NROWS, 128, 0, stream>>>(sent_rep, dvtm, dsc, tsc, tse, inp);
    gemm_kernel<true,true><<<dim3(128, 2), 256, 0, stream>>>(inp, BW1, b1, hdd, NROWS, 128, 512);
    logits_kernel<<<2048, 256, 0, stream>>>(hdd, W2, b2, out);
}

// Round 8
// 345.612 us; speedup vs baseline: 1.1556x; 1.1556x over previous
//
#include <hip/hip_runtime.h>
#include <hip/hip_bf16.h>
#include <cstdint>

// Problem constants
#define Bk 32
#define Sk 256
#define Wk 32
#define Tk 16
#define Ek 300
#define Hk 128
#define Dk 128
#define NROWS (Bk*Sk)          // 8192
#define GI_N  (3*Hk*2)         // 768
#define KPAD  320              // 300 padded to multiple of 32

typedef __attribute__((ext_vector_type(8))) short short8v;
typedef __attribute__((ext_vector_type(4))) float f32x4;

// ---------------- helpers ----------------
__device__ __forceinline__ float fast_sigmoid(float x) {
    return 1.f / (1.f + __expf(-x));
}
__device__ __forceinline__ float fast_tanh(float x) {
    float ax = fabsf(x);
    float e = __expf(2.f * ax);
    float t = 1.f - 2.f / (1.f + e);
    return copysignf(t, x);
}
__device__ __forceinline__ void barrier_lgkm() {
    asm volatile("s_waitcnt lgkmcnt(0)" ::: "memory");
    __builtin_amdgcn_s_barrier();
}
__device__ __forceinline__ void fma44(const float4& a, const float4& b, float (&c)[4][4]) {
    c[0][0]=fmaf(a.x,b.x,c[0][0]); c[0][1]=fmaf(a.x,b.y,c[0][1]); c[0][2]=fmaf(a.x,b.z,c[0][2]); c[0][3]=fmaf(a.x,b.w,c[0][3]);
    c[1][0]=fmaf(a.y,b.x,c[1][0]); c[1][1]=fmaf(a.y,b.y,c[1][1]); c[1][2]=fmaf(a.y,b.z,c[1][2]); c[1][3]=fmaf(a.y,b.w,c[1][3]);
    c[2][0]=fmaf(a.z,b.x,c[2][0]); c[2][1]=fmaf(a.z,b.y,c[2][1]); c[2][2]=fmaf(a.z,b.z,c[2][2]); c[2][3]=fmaf(a.z,b.w,c[2][3]);
    c[3][0]=fmaf(a.w,b.x,c[3][0]); c[3][1]=fmaf(a.w,b.y,c[3][1]); c[3][2]=fmaf(a.w,b.z,c[3][2]); c[3][3]=fmaf(a.w,b.w,c[3][3]);
}
// fp32 -> bf16 (RNE), finite inputs
__device__ __forceinline__ unsigned short f2bf(float f) {
    uint32_t u = __float_as_uint(f);
    uint32_t r = (u + 0x7FFFu + ((u >> 16) & 1u)) >> 16;
    return (unsigned short)r;
}
__device__ __forceinline__ float bf2f(unsigned short h) {
    return __uint_as_float(((uint32_t)h) << 16);
}

// ---------------- pack kernel ----------------
// Bgt_hi/lo [768][320] bf16 = concat(Wih_f,Wih_b) transposed-to-[n][k], split.
// bias_gi[768] fp32. Wswt [512][256] bf16 = Watt rows 256..511 transposed.
// BW1 [512][128] fp32 = W1^T.
__global__ __launch_bounds__(256) void pack_kernel(
    const float* __restrict__ Wf, const float* __restrict__ Wb,
    const float* __restrict__ bf, const float* __restrict__ bb,
    const float* __restrict__ Watt, const float* __restrict__ W1,
    unsigned short* __restrict__ Bgt_hi, unsigned short* __restrict__ Bgt_lo,
    float* __restrict__ bias_gi, unsigned short* __restrict__ Wswt,
    float* __restrict__ BW1)
{
    int idx = blockIdx.x * 256 + threadIdx.x;
    if (idx < 768 * KPAD) {
        int n = idx / KPAD, k = idx % KPAD;
        float v = 0.f;
        if (k < 300) v = (n < 384) ? Wf[n * 300 + k] : Wb[(n - 384) * 300 + k];
        unsigned short h = f2bf(v);
        Bgt_hi[idx] = h;
        Bgt_lo[idx] = f2bf(v - bf2f(h));
    }
    if (idx < 768) bias_gi[idx] = (idx < 384) ? bf[idx] : bb[idx - 384];
    if (idx < 512 * 256) {
        int n = idx >> 8, k = idx & 255;
        Wswt[idx] = f2bf(Watt[(size_t)(256 + k) * 512 + n]);
    }
    if (idx < 512 * 128) {
        int k = idx >> 7, n = idx & 127;
        BW1[idx] = W1[n * 512 + k];
    }
}

// ---------------- embedding mean -> bf16 hi/lo [8192][320] ----------------
__global__ __launch_bounds__(256) void embed_mean_kernel(
    const int* __restrict__ wids, const float* __restrict__ table,
    unsigned short* __restrict__ Ahi, unsigned short* __restrict__ Alo)
{
    int wv = (blockIdx.x << 2) + (threadIdx.x >> 6);
    int lane = threadIdx.x & 63;
    if (wv >= NROWS) return;
    const int* idp = wids + (size_t)wv * Wk;
    float4 a0 = {0,0,0,0}, a1 = {0,0,0,0};
    #pragma unroll 4
    for (int w = 0; w < Wk; ++w) {
        int id = idp[w];
        const float4* r4 = reinterpret_cast<const float4*>(table + (size_t)id * Ek);
        float4 v0 = r4[lane];
        a0.x += v0.x; a0.y += v0.y; a0.z += v0.z; a0.w += v0.w;
        if (lane < 11) {
            float4 v1 = r4[64 + lane];
            a1.x += v1.x; a1.y += v1.y; a1.z += v1.z; a1.w += v1.w;
        }
    }
    const float sc = 1.f / 32.f;
    unsigned short* hp = Ahi + (size_t)wv * KPAD;
    unsigned short* lp = Alo + (size_t)wv * KPAD;
    {
        float v[4] = {a0.x*sc, a0.y*sc, a0.z*sc, a0.w*sc};
        ushort4 h, l;
        h.x=f2bf(v[0]); h.y=f2bf(v[1]); h.z=f2bf(v[2]); h.w=f2bf(v[3]);
        l.x=f2bf(v[0]-bf2f(h.x)); l.y=f2bf(v[1]-bf2f(h.y));
        l.z=f2bf(v[2]-bf2f(h.z)); l.w=f2bf(v[3]-bf2f(h.w));
        *reinterpret_cast<ushort4*>(hp + lane*4) = h;
        *reinterpret_cast<ushort4*>(lp + lane*4) = l;
    }
    if (lane < 11) {
        float v[4] = {a1.x*sc, a1.y*sc, a1.z*sc, a1.w*sc};
        ushort4 h, l;
        h.x=f2bf(v[0]); h.y=f2bf(v[1]); h.z=f2bf(v[2]); h.w=f2bf(v[3]);
        l.x=f2bf(v[0]-bf2f(h.x)); l.y=f2bf(v[1]-bf2f(h.y));
        l.z=f2bf(v[2]-bf2f(h.z)); l.w=f2bf(v[3]-bf2f(h.w));
        *reinterpret_cast<ushort4*>(hp + 256 + lane*4) = h;
        *reinterpret_cast<ushort4*>(lp + 256 + lane*4) = l;
    } else if (lane < 16) {
        ushort4 z = {0,0,0,0};
        *reinterpret_cast<ushort4*>(hp + 256 + lane*4) = z;   // cols 300..319 pad
        *reinterpret_cast<ushort4*>(lp + 256 + lane*4) = z;
    }
}

// ---------------- fp32 -> bf16 (hi only) converter ----------------
__global__ __launch_bounds__(256) void cvt_bf16_kernel(
    const float* __restrict__ src, unsigned short* __restrict__ dst, int n8)
{
    int i = blockIdx.x * 256 + threadIdx.x;
    if (i >= n8) return;
    const float4* s = reinterpret_cast<const float4*>(src) + (size_t)i * 2;
    float4 v0 = s[0], v1 = s[1];
    unsigned short r[8];
    r[0]=f2bf(v0.x); r[1]=f2bf(v0.y); r[2]=f2bf(v0.z); r[3]=f2bf(v0.w);
    r[4]=f2bf(v1.x); r[5]=f2bf(v1.y); r[6]=f2bf(v1.z); r[7]=f2bf(v1.w);
    *reinterpret_cast<short8v*>(dst + (size_t)i * 8) = *reinterpret_cast<short8v*>(r);
}

// ---------------- MFMA bf16 GEMM: C[M,N] = A @ Bt^T (+bias) ---------------
// A as bf16 [M][Kp] (hi, + lo for PASSES=3); B pre-transposed [N][Kp] bf16.
// 3-pass split-bf16 (Ah*Bh + Al*Bh + Ah*Bl) ~ fp32 accuracy.
// Tile 128x128, BK=32, 256 threads = 4 waves (2x2 of 64x64 wave-tiles).
// Fragment layout (guide-verified): A-frag row=lane&15, k=(lane>>4)*8+i;
// B-frag = Bt row n=lane&15, same k; C/D col=lane&15, row=(lane>>4)*4+r.
// LDS rows padded to 40 bf16 -> conflict-free ds_read_b128.
// Requires M%128==0, N%128==0, Kp%32==0.
template<int PASSES, bool BIAS>
__global__ __launch_bounds__(256) void mfma_gemm_kernel(
    const unsigned short* __restrict__ Ahi, const unsigned short* __restrict__ Alo,
    const unsigned short* __restrict__ Bthi, const unsigned short* __restrict__ Btlo,
    const float* __restrict__ bias, float* __restrict__ C,
    int M, int N, int Kp)
{
    __shared__ unsigned short At_h[128][40];
    __shared__ unsigned short Bt_h[128][40];
    __shared__ unsigned short At_l[128][40];
    __shared__ unsigned short Bt_l[128][40];
    const int tid = threadIdx.x;
    const int m0 = blockIdx.x * 128, n0 = blockIdx.y * 128;
    const int lane = tid & 63;
    const int wave = tid >> 6;
    const int wr = (wave >> 1) * 64, wc = (wave & 1) * 64;
    const int l15 = lane & 15, l4 = lane >> 4;
    f32x4 acc[4][4] = {};

    const int srow = tid >> 1;          // 0..127
    const int scol = (tid & 1) * 16;    // bf16 col base 0/16

    for (int k0 = 0; k0 < Kp; k0 += 32) {
        {
            const unsigned short* ag = Ahi + (size_t)(m0 + srow) * Kp + k0 + scol;
            *reinterpret_cast<short8v*>(&At_h[srow][scol])     = *reinterpret_cast<const short8v*>(ag);
            *reinterpret_cast<short8v*>(&At_h[srow][scol + 8]) = *reinterpret_cast<const short8v*>(ag + 8);
            const unsigned short* bg = Bthi + (size_t)(n0 + srow) * Kp + k0 + scol;
            *reinterpret_cast<short8v*>(&Bt_h[srow][scol])     = *reinterpret_cast<const short8v*>(bg);
            *reinterpret_cast<short8v*>(&Bt_h[srow][scol + 8]) = *reinterpret_cast<const short8v*>(bg + 8);
            if (PASSES > 1) {
                const unsigned short* ag2 = Alo + (size_t)(m0 + srow) * Kp + k0 + scol;
                *reinterpret_cast<short8v*>(&At_l[srow][scol])     = *reinterpret_cast<const short8v*>(ag2);
                *reinterpret_cast<short8v*>(&At_l[srow][scol + 8]) = *reinterpret_cast<const short8v*>(ag2 + 8);
                const unsigned short* bg2 = Btlo + (size_t)(n0 + srow) * Kp + k0 + scol;
                *reinterpret_cast<short8v*>(&Bt_l[srow][scol])     = *reinterpret_cast<const short8v*>(bg2);
                *reinterpret_cast<short8v*>(&Bt_l[srow][scol + 8]) = *reinterpret_cast<const short8v*>(bg2 + 8);
            }
        }
        __syncthreads();
        short8v a_h[4], b_h[4], a_l[4], b_l[4];
        #pragma unroll
        for (int f = 0; f < 4; ++f) {
            a_h[f] = *reinterpret_cast<const short8v*>(&At_h[wr + f*16 + l15][l4*8]);
            b_h[f] = *reinterpret_cast<const short8v*>(&Bt_h[wc + f*16 + l15][l4*8]);
            if (PASSES > 1) {
                a_l[f] = *reinterpret_cast<const short8v*>(&At_l[wr + f*16 + l15][l4*8]);
                b_l[f] = *reinterpret_cast<const short8v*>(&Bt_l[wc + f*16 + l15][l4*8]);
            }
        }
        #pragma unroll
        for (int i = 0; i < 4; ++i) {
            #pragma unroll
            for (int j = 0; j < 4; ++j) {
                acc[i][j] = __builtin_amdgcn_mfma_f32_16x16x32_bf16(a_h[i], b_h[j], acc[i][j], 0, 0, 0);
                if (PASSES > 1) {
                    acc[i][j] = __builtin_amdgcn_mfma_f32_16x16x32_bf16(a_l[i], b_h[j], acc[i][j], 0, 0, 0);
                    acc[i][j] = __builtin_amdgcn_mfma_f32_16x16x32_bf16(a_h[i], b_l[j], acc[i][j], 0, 0, 0);
                }
            }
        }
        __syncthreads();
    }
    #pragma unroll
    for (int i = 0; i < 4; ++i) {
        #pragma unroll
        for (int j = 0; j < 4; ++j) {
            int col = n0 + wc + j * 16 + l15;
            float badd = BIAS ? bias[col] : 0.f;
            #pragma unroll
            for (int r = 0; r < 4; ++r) {
                int row = m0 + wr + i * 16 + l4 * 4 + r;
                C[(size_t)row * N + col] = acc[i][j][r] + badd;
            }
        }
    }
}

// ---------------- 64x64 fp32 GEMM (small shapes) ----------------
template<bool BIAS, bool RELU>
__global__ __launch_bounds__(256) void gemm_kernel(
    const float* __restrict__ A, const float* __restrict__ B,
    const float* __restrict__ bias, float* __restrict__ C,
    int M, int N, int K)
{
    __shared__ float As[64][68];
    __shared__ float Bs[64][68];
    const int tid = threadIdx.x;
    const int m0 = blockIdx.x * 64;
    const int n0 = blockIdx.y * 64;
    const int tx = tid & 15, ty = tid >> 4;
    const int lr = tid >> 2;
    const int lc = tid & 3;
    float acc[4][4] = {};

    for (int k0 = 0; k0 < K; k0 += 64) {
        #pragma unroll
        for (int i = 0; i < 4; ++i) {
            int kk = lc * 4 + i * 16;
            int gm = m0 + lr;
            int gk = k0 + kk;
            float4 v = {0,0,0,0};
            if (gm < M && gk < K)
                v = *reinterpret_cast<const float4*>(A + (size_t)gm * K + gk);
            As[kk+0][lr] = v.x; As[kk+1][lr] = v.y; As[kk+2][lr] = v.z; As[kk+3][lr] = v.w;
        }
        #pragma unroll
        for (int i = 0; i < 4; ++i) {
            int nn = lc * 4 + i * 16;
            int gk = k0 + lr;
            float4 v = {0,0,0,0};
            if (gk < K)
                v = *reinterpret_cast<const float4*>(B + (size_t)gk * N + n0 + nn);
            *reinterpret_cast<float4*>(&Bs[lr][nn]) = v;
        }
        __syncthreads();
        #pragma unroll 8
        for (int k = 0; k < 64; ++k) {
            float4 av = *reinterpret_cast<const float4*>(&As[k][ty*4]);
            float4 bv = *reinterpret_cast<const float4*>(&Bs[k][tx*4]);
            fma44(av, bv, acc);
        }
        __syncthreads();
    }
    #pragma unroll
    for (int r = 0; r < 4; ++r) {
        int row = m0 + ty * 4 + r;
        if (row < M) {
            float4 v = {acc[r][0], acc[r][1], acc[r][2], acc[r][3]};
            if (BIAS) {
                const float* bp = bias + n0 + tx * 4;
                v.x += bp[0]; v.y += bp[1]; v.z += bp[2]; v.w += bp[3];
            }
            if (RELU) {
                v.x = fmaxf(v.x, 0.f); v.y = fmaxf(v.y, 0.f);
                v.z = fmaxf(v.z, 0.f); v.w = fmaxf(v.w, 0.f);
            }
            *reinterpret_cast<float4*>(C + (size_t)row * N + n0 + tx * 4) = v;
        }
    }
}

// ---------------- GRU scan (r6: single barrier / step) ----------------
__global__ __launch_bounds__(512, 1) void gru_scan_kernel(
    const float* __restrict__ gi,       // [8192, 768], col = dir*384 + g
    const float* __restrict__ Whh_f, const float* __restrict__ Whh_b,
    const float* __restrict__ bhh_f, const float* __restrict__ bhh_b,
    float* __restrict__ sent_rep,       // [8192, 256], col = dir*128 + j
    float* __restrict__ hT)             // [2][32][128]
{
    const int blk = blockIdx.x;
    const int dir = blk >> 5;
    const int b   = blk & 31;
    const int t = threadIdx.x;
    const int lane = t & 63;
    const int w_id = t >> 6;
    const int q = lane >> 4;          // h segment 0..3
    const int m = lane & 15;
    const int j = w_id * 16 + m;      // hidden index 0..127
    const float* Whh = dir ? Whh_b : Whh_f;
    const float* bhh = dir ? bhh_b : bhh_f;
    __shared__ float hbufA[144];   // 4 segs of 32, padded stride 36
    __shared__ float hbufB[144];

    const float* wr0 = Whh + (size_t)j * 128 + 32 * q;
    const float* wr1 = wr0 + 128 * 128;
    const float* wr2 = wr0 + 256 * 128;
    float4 wA0 = *reinterpret_cast<const float4*>(wr0 +  0);
    float4 wA1 = *reinterpret_cast<const float4*>(wr0 +  4);
    float4 wA2 = *reinterpret_cast<const float4*>(wr0 +  8);
    float4 wA3 = *reinterpret_cast<const float4*>(wr0 + 12);
    float4 wA4 = *reinterpret_cast<const float4*>(wr0 + 16);
    float4 wA5 = *reinterpret_cast<const float4*>(wr0 + 20);
    float4 wA6 = *reinterpret_cast<const float4*>(wr0 + 24);
    float4 wA7 = *reinterpret_cast<const float4*>(wr0 + 28);
    float4 wB0 = *reinterpret_cast<const float4*>(wr1 +  0);
    float4 wB1 = *reinterpret_cast<const float4*>(wr1 +  4);
    float4 wB2 = *reinterpret_cast<const float4*>(wr1 +  8);
    float4 wB3 = *reinterpret_cast<const float4*>(wr1 + 12);
    float4 wB4 = *reinterpret_cast<const float4*>(wr1 + 16);
    float4 wB5 = *reinterpret_cast<const float4*>(wr1 + 20);
    float4 wB6 = *reinterpret_cast<const float4*>(wr1 + 24);
    float4 wB7 = *reinterpret_cast<const float4*>(wr1 + 28);
    float4 wC0 = *reinterpret_cast<const float4*>(wr2 +  0);
    float4 wC1 = *reinterpret_cast<const float4*>(wr2 +  4);
    float4 wC2 = *reinterpret_cast<const float4*>(wr2 +  8);
    float4 wC3 = *reinterpret_cast<const float4*>(wr2 + 12);
    float4 wC4 = *reinterpret_cast<const float4*>(wr2 + 16);
    float4 wC5 = *reinterpret_cast<const float4*>(wr2 + 20);
    float4 wC6 = *reinterpret_cast<const float4*>(wr2 + 24);
    float4 wC7 = *reinterpret_cast<const float4*>(wr2 + 28);
    const float br = bhh[j];
    const float bz = bhh[128 + j];
    const float bn = bhh[256 + j];

    if (t < 144) { hbufA[t] = 0.f; hbufB[t] = 0.f; }

    const int ji = 36 * (j >> 5) + (j & 31);   // padded write index
    const float* gbase = gi + (size_t)(b * Sk) * GI_N + dir * 384 + j;
    float hold = 0.f;
    float gir = 0.f, giz = 0.f, gin_ = 0.f;
    {
        const int s0 = dir ? (Sk - 1) : 0;
        const float* gp = gbase + (size_t)s0 * GI_N;
        gir = gp[0]; giz = gp[128]; gin_ = gp[256];
    }
    __syncthreads();

    #define STEP(RD, WR, SEXPR) { \
        const int s = (SEXPR); \
        const float4* hseg = reinterpret_cast<const float4*>(RD) + 9 * q; \
        float pA = 0.f, pB = 0.f, pC = 0.f; \
        { float4 h4; \
          h4 = hseg[0]; \
          pA=fmaf(wA0.x,h4.x,pA); pA=fmaf(wA0.y,h4.y,pA); pA=fmaf(wA0.z,h4.z,pA); pA=fmaf(wA0.w,h4.w,pA); \
          pB=fmaf(wB0.x,h4.x,pB); pB=fmaf(wB0.y,h4.y,pB); pB=fmaf(wB0.z,h4.z,pB); pB=fmaf(wB0.w,h4.w,pB); \
          pC=fmaf(wC0.x,h4.x,pC); pC=fmaf(wC0.y,h4.y,pC); pC=fmaf(wC0.z,h4.z,pC); pC=fmaf(wC0.w,h4.w,pC); \
          h4 = hseg[1]; \
          pA=fmaf(wA1.x,h4.x,pA); pA=fmaf(wA1.y,h4.y,pA); pA=fmaf(wA1.z,h4.z,pA); pA=fmaf(wA1.w,h4.w,pA); \
          pB=fmaf(wB1.x,h4.x,pB); pB=fmaf(wB1.y,h4.y,pB); pB=fmaf(wB1.z,h4.z,pB); pB=fmaf(wB1.w,h4.w,pB); \
          pC=fmaf(wC1.x,h4.x,pC); pC=fmaf(wC1.y,h4.y,pC); pC=fmaf(wC1.z,h4.z,pC); pC=fmaf(wC1.w,h4.w,pC); \
          h4 = hseg[2]; \
          pA=fmaf(wA2.x,h4.x,pA); pA=fmaf(wA2.y,h4.y,pA); pA=fmaf(wA2.z,h4.z,pA); pA=fmaf(wA2.w,h4.w,pA); \
          pB=fmaf(wB2.x,h4.x,pB); pB=fmaf(wB2.y,h4.y,pB); pB=fmaf(wB2.z,h4.z,pB); pB=fmaf(wB2.w,h4.w,pB); \
          pC=fmaf(wC2.x,h4.x,pC); pC=fmaf(wC2.y,h4.y,pC); pC=fmaf(wC2.z,h4.z,pC); pC=fmaf(wC2.w,h4.w,pC); \
          h4 = hseg[3]; \
          pA=fmaf(wA3.x,h4.x,pA); pA=fmaf(wA3.y,h4.y,pA); pA=fmaf(wA3.z,h4.z,pA); pA=fmaf(wA3.w,h4.w,pA); \
          pB=fmaf(wB3.x,h4.x,pB); pB=fmaf(wB3.y,h4.y,pB); pB=fmaf(wB3.z,h4.z,pB); pB=fmaf(wB3.w,h4.w,pB); \
          pC=fmaf(wC3.x,h4.x,pC); pC=fmaf(wC3.y,h4.y,pC); pC=fmaf(wC3.z,h4.z,pC); pC=fmaf(wC3.w,h4.w,pC); \
          h4 = hseg[4]; \
          pA=fmaf(wA4.x,h4.x,pA); pA=fmaf(wA4.y,h4.y,pA); pA=fmaf(wA4.z,h4.z,pA); pA=fmaf(wA4.w,h4.w,pA); \
          pB=fmaf(wB4.x,h4.x,pB); pB=fmaf(wB4.y,h4.y,pB); pB=fmaf(wB4.z,h4.z,pB); pB=fmaf(wB4.w,h4.w,pB); \
          pC=fmaf(wC4.x,h4.x,pC); pC=fmaf(wC4.y,h4.y,pC); pC=fmaf(wC4.z,h4.z,pC); pC=fmaf(wC4.w,h4.w,pC); \
          h4 = hseg[5]; \
          pA=fmaf(wA5.x,h4.x,pA); pA=fmaf(wA5.y,h4.y,pA); pA=fmaf(wA5.z,h4.z,pA); pA=fmaf(wA5.w,h4.w,pA); \
          pB=fmaf(wB5.x,h4.x,pB); pB=fmaf(wB5.y,h4.y,pB); pB=fmaf(wB5.z,h4.z,pB); pB=fmaf(wB5.w,h4.w,pB); \
          pC=fmaf(wC5.x,h4.x,pC); pC=fmaf(wC5.y,h4.y,pC); pC=fmaf(wC5.z,h4.z,pC); pC=fmaf(wC5.w,h4.w,pC); \
          h4 = hseg[6]; \
          pA=fmaf(wA6.x,h4.x,pA); pA=fmaf(wA6.y,h4.y,pA); pA=fmaf(wA6.z,h4.z,pA); pA=fmaf(wA6.w,h4.w,pA); \
          pB=fmaf(wB6.x,h4.x,pB); pB=fmaf(wB6.y,h4.y,pB); pB=fmaf(wB6.z,h4.z,pB); pB=fmaf(wB6.w,h4.w,pB); \
          pC=fmaf(wC6.x,h4.x,pC); pC=fmaf(wC6.y,h4.y,pC); pC=fmaf(wC6.z,h4.z,pC); pC=fmaf(wC6.w,h4.w,pC); \
          h4 = hseg[7]; \
          pA=fmaf(wA7.x,h4.x,pA); pA=fmaf(wA7.y,h4.y,pA); pA=fmaf(wA7.z,h4.z,pA); pA=fmaf(wA7.w,h4.w,pA); \
          pB=fmaf(wB7.x,h4.x,pB); pB=fmaf(wB7.y,h4.y,pB); pB=fmaf(wB7.z,h4.z,pB); pB=fmaf(wB7.w,h4.w,pB); \
          pC=fmaf(wC7.x,h4.x,pC); pC=fmaf(wC7.y,h4.y,pC); pC=fmaf(wC7.z,h4.z,pC); pC=fmaf(wC7.w,h4.w,pC); } \
        pA += __shfl_xor(pA, 16); pA += __shfl_xor(pA, 32); \
        pB += __shfl_xor(pB, 16); pB += __shfl_xor(pB, 32); \
        pC += __shfl_xor(pC, 16); pC += __shfl_xor(pC, 32); \
        if (q == 0) { \
            float r = fast_sigmoid(gir + pA + br); \
            float z = fast_sigmoid(giz + pB + bz); \
            float n = fast_tanh(gin_ + r * (pC + bn)); \
            hold = (1.f - z) * n + z * hold; \
            (WR)[ji] = hold; \
            sent_rep[(size_t)(b * Sk + s) * 256 + dir * 128 + j] = hold; \
            const int sn = dir ? (s > 0 ? s - 1 : 0) : (s + 1 < Sk ? s + 1 : Sk - 1); \
            const float* gp = gbase + (size_t)sn * GI_N; \
            gir = gp[0]; giz = gp[128]; gin_ = gp[256]; \
        } \
        barrier_lgkm(); \
    }

    for (int step = 0; step < Sk; step += 2) {
        STEP(hbufA, hbufB, dir ? (Sk - 1 - step) : step);
        STEP(hbufB, hbufA, dir ? (Sk - 2 - step) : (step + 1));
    }
    #undef STEP

    if (q == 0) hT[dir * 4096 + b * 128 + j] = hold;
}

// ---------------- prep: doc_vec + topic_mat ----------------
__device__ __forceinline__ float4 sr_load_guard(const float* sr, int b, int sidx, int j4) {
    if (sidx < 0 || sidx >= Sk) { float4 z = {0,0,0,0}; return z; }
    return reinterpret_cast<const float4*>(sr)[(size_t)(b * Sk + sidx) * 64 + j4];
}
__global__ __launch_bounds__(64) void prep_kernel(
    const int* __restrict__ tse, const float* __restrict__ sent_rep,
    const float* __restrict__ hT, float* __restrict__ dvtm)
{
    const int b = blockIdx.x;
    const int t = blockIdx.y;
    const int j4 = threadIdx.x;   // 0..63 (float4 col)
    if (t == 16) {
        int dir = b >> 4;
        int bb = 2 * (b & 15) + (j4 >> 5);
        int jj4 = j4 & 31;
        float4 v = reinterpret_cast<const float4*>(hT)[dir * 1024 + bb * 32 + jj4];
        reinterpret_cast<float4*>(dvtm)[b * 64 + j4] = v;
    } else {
        int st = tse[b * 32 + t * 2];
        int en = tse[b * 32 + t * 2 + 1];
        float4 va, vb;
        if (j4 < 32) {
            va = sr_load_guard(sent_rep, b, en - 1, j4);
            vb = sr_load_guard(sent_rep, b, st - 2, j4);
        } else {
            va = sr_load_guard(sent_rep, b, st - 1, j4);
            vb = sr_load_guard(sent_rep, b, en, j4);
        }
        float4 v = {va.x - vb.x, va.y - vb.y, va.z - vb.z, va.w - vb.w};
        reinterpret_cast<float4*>(dvtm)[(32 + b * 16 + t) * 64 + j4] = v;
    }
}

// ---------------- scores ----------------
__global__ __launch_bounds__(256) void scores_kernel(
    const float* __restrict__ SW,    // [8192,512]
    const float* __restrict__ dptp,  // [544,512]
    const float* __restrict__ vatt,  // [512]
    const int* __restrict__ tse,
    float* __restrict__ dsc, float* __restrict__ tsc)
{
    int row = (blockIdx.x << 2) + (threadIdx.x >> 6);
    int lane = threadIdx.x & 63;
    if (row >= NROWS) return;
    int b = row >> 8, s = row & 255;
    int ti = 0;
    #pragma unroll
    for (int t = 1; t < 16; ++t) ti += (s >= tse[b * 32 + t * 2] - 1) ? 1 : 0;
    const float4* swr = reinterpret_cast<const float4*>(SW + (size_t)row * 512);
    const float4* dpr = reinterpret_cast<const float4*>(dptp + (size_t)b * 512);
    const float4* tpr = reinterpret_cast<const float4*>(dptp + (size_t)(32 + b * 16 + ti) * 512);
    const float4* vv  = reinterpret_cast<const float4*>(vatt);
    float sd = 0.f, st = 0.f;
    #pragma unroll
    for (int q = 0; q < 2; ++q) {
        int i = lane * 2 + q;
        float4 sw = swr[i], dp = dpr[i], tp = tpr[i], v = vv[i];
        sd += fast_tanh(sw.x + dp.x) * v.x + fast_tanh(sw.y + dp.y) * v.y
            + fast_tanh(sw.z + dp.z) * v.z + fast_tanh(sw.w + dp.w) * v.w;
        st += fast_tanh(sw.x + tp.x) * v.x + fast_tanh(sw.y + tp.y) * v.y
            + fast_tanh(sw.z + tp.z) * v.z + fast_tanh(sw.w + tp.w) * v.w;
    }
    #pragma unroll
    for (int off = 32; off; off >>= 1) {
        sd += __shfl_xor(sd, off);
        st += __shfl_xor(st, off);
    }
    if (lane == 0) { dsc[row] = sd; tsc[row] = st; }
}

// ---------------- softmax ----------------
__global__ __launch_bounds__(256) void softmax_kernel(float* __restrict__ dsc, float* __restrict__ tsc)
{
    const int b = blockIdx.x, sidx = threadIdx.x;
    const int lane = sidx & 63, wid = sidx >> 6;
    __shared__ float rd[4], rt[4];
    float d = dsc[b * Sk + sidx];
    float t = tsc[b * Sk + sidx];
    float md = d, mt = t;
    #pragma unroll
    for (int off = 32; off; off >>= 1) {
        md = fmaxf(md, __shfl_xor(md, off));
        mt = fmaxf(mt, __shfl_xor(mt, off));
    }
    if (lane == 0) { rd[wid] = md; rt[wid] = mt; }
    __syncthreads();
    md = fmaxf(fmaxf(rd[0], rd[1]), fmaxf(rd[2], rd[3]));
    mt = fmaxf(fmaxf(rt[0], rt[1]), fmaxf(rt[2], rt[3]));
    float ed = __expf(d - md), et = __expf(t - mt);
    float sd = ed, stt = et;
    #pragma unroll
    for (int off = 32; off; off >>= 1) {
        sd += __shfl_xor(sd, off);
        stt += __shfl_xor(stt, off);
    }
    __syncthreads();
    if (lane == 0) { rd[wid] = sd; rt[wid] = stt; }
    __syncthreads();
    sd = rd[0] + rd[1] + rd[2] + rd[3];
    stt = rt[0] + rt[1] + rt[2] + rt[3];
    dsc[b * Sk + sidx] = ed / sd;
    tsc[b * Sk + sidx] = et / stt;
}

// ---------------- build inp = [sent_rep, context] ----------------
__global__ __launch_bounds__(128) void build_inp_kernel(
    const float* __restrict__ sent_rep, const float* __restrict__ dvtm,
    const float* __restrict__ dw, const float* __restrict__ tw,
    const int* __restrict__ tse, float* __restrict__ inp)
{
    int row = blockIdx.x;
    int b = row >> 8, s = row & 255;
    int f4c = threadIdx.x;   // 0..127
    float4 v;
    if (f4c < 64) {
        v = reinterpret_cast<const float4*>(sent_rep)[(size_t)row * 64 + f4c];
    } else {
        int ti = 0;
        #pragma unroll
        for (int t = 1; t < 16; ++t) ti += (s >= tse[b * 32 + t * 2] - 1) ? 1 : 0;
        float dwv = dw[row], twv = tw[row];
        int j4 = f4c - 64;
        float4 dv = reinterpret_cast<const float4*>(dvtm)[b * 64 + j4];
        float4 tm = reinterpret_cast<const float4*>(dvtm)[(32 + b * 16 + ti) * 64 + j4];
        v.x = dwv * dv.x + twv * tm.x;
        v.y = dwv * dv.y + twv * tm.y;
        v.z = dwv * dv.z + twv * tm.z;
        v.w = dwv * dv.w + twv * tm.w;
    }
    reinterpret_cast<float4*>(inp)[(size_t)row * 128 + f4c] = v;
}

// ---------------- final logits ----------------
__global__ __launch_bounds__(256) void logits_kernel(
    const float* __restrict__ hdd, const float* __restrict__ W2,
    const float* __restrict__ b2, float* __restrict__ out)
{
    int row = (blockIdx.x << 2) + (threadIdx.x >> 6);
    int lane = threadIdx.x & 63;
    if (row >= NROWS) return;
    float acc = hdd[(size_t)row * 128 + lane] * W2[lane]
              + hdd[(size_t)row * 128 + 64 + lane] * W2[64 + lane];
    #pragma unroll
    for (int off = 32; off; off >>= 1) acc += __shfl_xor(acc, off);
    if (lane == 0) out[row] = acc + b2[0];
}

// ---------------- launch ----------------
extern "C" void kernel_launch(void* const* d_in, const int* in_sizes, int n_in,
                              void* d_out, int out_size, void* d_ws, size_t ws_size,
                              hipStream_t stream)
{
    const int*   wids  = (const int*)d_in[0];
    const int*   tse   = (const int*)d_in[1];
    const float* table = (const float*)d_in[2];
    const float* Wihf  = (const float*)d_in[3];
    const float* Whhf  = (const float*)d_in[4];
    const float* bihf  = (const float*)d_in[5];
    const float* bhhf  = (const float*)d_in[6];
    const float* Wihb  = (const float*)d_in[7];
    const float* Whhb  = (const float*)d_in[8];
    const float* bihb  = (const float*)d_in[9];
    const float* bhhb  = (const float*)d_in[10];
    const float* vatt  = (const float*)d_in[11];
    const float* Watt  = (const float*)d_in[12];
    const float* W1    = (const float*)d_in[13];
    const float* b1    = (const float*)d_in[14];
    const float* W2    = (const float*)d_in[15];
    const float* b2    = (const float*)d_in[16];
    float* ws = (float*)d_ws;
    float* out = (float*)d_out;

    // layout (float units)
    unsigned short* Ahi   = (unsigned short*)(ws + 0);          // 8192*320 bf16 = 1,310,720 f
    unsigned short* Alo   = (unsigned short*)(ws + 1310720);    // 1,310,720 f
    float* gi             = ws + 2621440;                       // 6,291,456
    float* sent_rep       = ws + 8912896;                       // 2,097,152
    unsigned short* SRhi  = (unsigned short*)(ws + 11010048);   // 8192*256 bf16 = 1,048,576 f
    float* hT             = ws + 12058624;                      // 8,192
    float* dvtm           = ws + 12066816;                      // 139,264
    float* dptp           = ws + 12206080;                      // 278,528
    float* dsc            = ws + 12484608;                      // 8,192
    float* tsc            = ws + 12492800;                      // 8,192
    unsigned short* BgtH  = (unsigned short*)(ws + 12500992);   // 768*320 = 122,880 f
    unsigned short* BgtL  = (unsigned short*)(ws + 12623872);   // 122,880 f
    float* bias_gi        = ws + 12746752;                      // 768
    unsigned short* Wswt  = (unsigned short*)(ws + 12747520);   // 512*256 = 65,536 f
    float* BW1            = ws + 12813056;                      // 65,536
    float* SW             = ws + 12878592;                      // 4,194,304 -> end 17,072,896
    // dead-zone reuse (Ahi/Alo/gi dead after scan):
    float* inp            = ws + 0;                             // 4,194,304
    float* hdd            = ws + 4194304;                       // 1,048,576

    if (ws_size < (size_t)17072896 * sizeof(float)) return;

    pack_kernel<<<960, 256, 0, stream>>>(Wihf, Wihb, bihf, bihb, Watt, W1,
                                         BgtH, BgtL, bias_gi, Wswt, BW1);
    embed_mean_kernel<<<2048, 256, 0, stream>>>(wids, table, Ahi, Alo);
    mfma_gemm_kernel<3, true><<<dim3(64, 6), 256, 0, stream>>>(
        Ahi, Alo, BgtH, BgtL, bias_gi, gi, NROWS, 768, KPAD);
    gru_scan_kernel<<<64, 512, 0, stream>>>(gi, Whhf, Whhb, bhhf, bhhb, sent_rep, hT);
    cvt_bf16_kernel<<<1024, 256, 0, stream>>>(sent_rep, SRhi, NROWS * 256 / 8);
    prep_kernel<<<dim3(32, 17), 64, 0, stream>>>(tse, sent_rep, hT, dvtm);
    mfma_gemm_kernel<1, false><<<dim3(64, 4), 256, 0, stream>>>(
        SRhi, nullptr, Wswt, nullptr, nullptr, SW, NROWS, 512, 256);
    gemm_kernel<false,false><<<dim3(9, 8), 256, 0, stream>>>(dvtm, Watt, nullptr, dptp, 544, 512, 256);
    scores_kernel<<<2048, 256, 0, stream>>>(SW, dptp, vatt, tse, dsc, tsc);
    softmax_kernel<<<32, 256, 0, stream>>>(dsc, tsc);
    build_inp_kernel<<<NROWS, 128, 0, stream>>>(sent_rep, dvtm, dsc, tsc, tse, inp);
    gemm_kernel<true,true><<<dim3(128, 2), 256, 0, stream>>>(inp, BW1, b1, hdd, NROWS, 128, 512);
    logits_kernel<<<2048, 256, 0, stream>>>(hdd, W2, b2, out);
}

// Round 9
// 338.981 us; speedup vs baseline: 1.1782x; 1.0196x over previous
//
#include <hip/hip_runtime.h>
#include <hip/hip_bf16.h>
#include <cstdint>

// Problem constants
#define Bk 32
#define Sk 256
#define Wk 32
#define Tk 16
#define Ek 300
#define Hk 128
#define Dk 128
#define NROWS (Bk*Sk)          // 8192
#define GI_N  (3*Hk*2)         // 768
#define KPAD  320              // 300 padded to multiple of 32

typedef __attribute__((ext_vector_type(8))) short short8v;
typedef __attribute__((ext_vector_type(4))) float f32x4;

// ---------------- helpers ----------------
__device__ __forceinline__ float fast_sigmoid(float x) {
    return 1.f / (1.f + __expf(-x));
}
__device__ __forceinline__ float fast_tanh(float x) {
    float ax = fabsf(x);
    float e = __expf(2.f * ax);
    float t = 1.f - 2.f / (1.f + e);
    return copysignf(t, x);
}
__device__ __forceinline__ void barrier_lgkm() {
    asm volatile("s_waitcnt lgkmcnt(0)" ::: "memory");
    __builtin_amdgcn_s_barrier();
}
__device__ __forceinline__ void fma44(const float4& a, const float4& b, float (&c)[4][4]) {
    c[0][0]=fmaf(a.x,b.x,c[0][0]); c[0][1]=fmaf(a.x,b.y,c[0][1]); c[0][2]=fmaf(a.x,b.z,c[0][2]); c[0][3]=fmaf(a.x,b.w,c[0][3]);
    c[1][0]=fmaf(a.y,b.x,c[1][0]); c[1][1]=fmaf(a.y,b.y,c[1][1]); c[1][2]=fmaf(a.y,b.z,c[1][2]); c[1][3]=fmaf(a.y,b.w,c[1][3]);
    c[2][0]=fmaf(a.z,b.x,c[2][0]); c[2][1]=fmaf(a.z,b.y,c[2][1]); c[2][2]=fmaf(a.z,b.z,c[2][2]); c[2][3]=fmaf(a.z,b.w,c[2][3]);
    c[3][0]=fmaf(a.w,b.x,c[3][0]); c[3][1]=fmaf(a.w,b.y,c[3][1]); c[3][2]=fmaf(a.w,b.z,c[3][2]); c[3][3]=fmaf(a.w,b.w,c[3][3]);
}
// fp32 -> bf16 (RNE), finite inputs
__device__ __forceinline__ unsigned short f2bf(float f) {
    uint32_t u = __float_as_uint(f);
    uint32_t r = (u + 0x7FFFu + ((u >> 16) & 1u)) >> 16;
    return (unsigned short)r;
}
__device__ __forceinline__ float bf2f(unsigned short h) {
    return __uint_as_float(((uint32_t)h) << 16);
}

// ---------------- pack kernel ----------------
__global__ __launch_bounds__(256) void pack_kernel(
    const float* __restrict__ Wf, const float* __restrict__ Wb,
    const float* __restrict__ bf, const float* __restrict__ bb,
    const float* __restrict__ Watt, const float* __restrict__ W1,
    unsigned short* __restrict__ Bgt_hi, unsigned short* __restrict__ Bgt_lo,
    float* __restrict__ bias_gi, unsigned short* __restrict__ Wswt,
    unsigned short* __restrict__ W1H, unsigned short* __restrict__ W1L)
{
    int idx = blockIdx.x * 256 + threadIdx.x;
    if (idx < 768 * KPAD) {
        int n = idx / KPAD, k = idx % KPAD;
        float v = 0.f;
        if (k < 300) v = (n < 384) ? Wf[n * 300 + k] : Wb[(n - 384) * 300 + k];
        unsigned short h = f2bf(v);
        Bgt_hi[idx] = h;
        Bgt_lo[idx] = f2bf(v - bf2f(h));
    }
    if (idx < 768) bias_gi[idx] = (idx < 384) ? bf[idx] : bb[idx - 384];
    if (idx < 512 * 256) {
        int n = idx >> 8, k = idx & 255;
        Wswt[idx] = f2bf(Watt[(size_t)(256 + k) * 512 + n]);
    }
    if (idx < 128 * 512) {      // W1 is [128][512] row-major == Bt layout [N][K]
        float v = W1[idx];
        unsigned short h = f2bf(v);
        W1H[idx] = h;
        W1L[idx] = f2bf(v - bf2f(h));
    }
}

// ---------------- embedding mean -> bf16 hi/lo [8192][320] ----------------
__global__ __launch_bounds__(256) void embed_mean_kernel(
    const int* __restrict__ wids, const float* __restrict__ table,
    unsigned short* __restrict__ Ahi, unsigned short* __restrict__ Alo)
{
    int wv = (blockIdx.x << 2) + (threadIdx.x >> 6);
    int lane = threadIdx.x & 63;
    if (wv >= NROWS) return;
    const int* idp = wids + (size_t)wv * Wk;
    float4 a0 = {0,0,0,0}, a1 = {0,0,0,0};
    #pragma unroll 4
    for (int w = 0; w < Wk; ++w) {
        int id = idp[w];
        const float4* r4 = reinterpret_cast<const float4*>(table + (size_t)id * Ek);
        float4 v0 = r4[lane];
        a0.x += v0.x; a0.y += v0.y; a0.z += v0.z; a0.w += v0.w;
        if (lane < 11) {
            float4 v1 = r4[64 + lane];
            a1.x += v1.x; a1.y += v1.y; a1.z += v1.z; a1.w += v1.w;
        }
    }
    const float sc = 1.f / 32.f;
    unsigned short* hp = Ahi + (size_t)wv * KPAD;
    unsigned short* lp = Alo + (size_t)wv * KPAD;
    {
        float v[4] = {a0.x*sc, a0.y*sc, a0.z*sc, a0.w*sc};
        ushort4 h, l;
        h.x=f2bf(v[0]); h.y=f2bf(v[1]); h.z=f2bf(v[2]); h.w=f2bf(v[3]);
        l.x=f2bf(v[0]-bf2f(h.x)); l.y=f2bf(v[1]-bf2f(h.y));
        l.z=f2bf(v[2]-bf2f(h.z)); l.w=f2bf(v[3]-bf2f(h.w));
        *reinterpret_cast<ushort4*>(hp + lane*4) = h;
        *reinterpret_cast<ushort4*>(lp + lane*4) = l;
    }
    if (lane < 11) {
        float v[4] = {a1.x*sc, a1.y*sc, a1.z*sc, a1.w*sc};
        ushort4 h, l;
        h.x=f2bf(v[0]); h.y=f2bf(v[1]); h.z=f2bf(v[2]); h.w=f2bf(v[3]);
        l.x=f2bf(v[0]-bf2f(h.x)); l.y=f2bf(v[1]-bf2f(h.y));
        l.z=f2bf(v[2]-bf2f(h.z)); l.w=f2bf(v[3]-bf2f(h.w));
        *reinterpret_cast<ushort4*>(hp + 256 + lane*4) = h;
        *reinterpret_cast<ushort4*>(lp + 256 + lane*4) = l;
    } else if (lane < 16) {
        ushort4 z = {0,0,0,0};
        *reinterpret_cast<ushort4*>(hp + 256 + lane*4) = z;
        *reinterpret_cast<ushort4*>(lp + 256 + lane*4) = z;
    }
}

// ---------------- fp32 -> bf16 (hi only) converter ----------------
__global__ __launch_bounds__(256) void cvt_bf16_kernel(
    const float* __restrict__ src, unsigned short* __restrict__ dst, int n8)
{
    int i = blockIdx.x * 256 + threadIdx.x;
    if (i >= n8) return;
    const float4* s = reinterpret_cast<const float4*>(src) + (size_t)i * 2;
    float4 v0 = s[0], v1 = s[1];
    unsigned short r[8];
    r[0]=f2bf(v0.x); r[1]=f2bf(v0.y); r[2]=f2bf(v0.z); r[3]=f2bf(v0.w);
    r[4]=f2bf(v1.x); r[5]=f2bf(v1.y); r[6]=f2bf(v1.z); r[7]=f2bf(v1.w);
    *reinterpret_cast<short8v*>(dst + (size_t)i * 8) = *reinterpret_cast<short8v*>(r);
}

// ---------------- MFMA bf16 GEMM: C[M,N] = A @ Bt^T (+bias, relu) ---------
template<int PASSES, bool BIAS, bool RELU>
__global__ __launch_bounds__(256) void mfma_gemm_kernel(
    const unsigned short* __restrict__ Ahi, const unsigned short* __restrict__ Alo,
    const unsigned short* __restrict__ Bthi, const unsigned short* __restrict__ Btlo,
    const float* __restrict__ bias, float* __restrict__ C,
    int M, int N, int Kp)
{
    __shared__ unsigned short At_h[128][40];
    __shared__ unsigned short Bt_h[128][40];
    __shared__ unsigned short At_l[128][40];
    __shared__ unsigned short Bt_l[128][40];
    const int tid = threadIdx.x;
    const int m0 = blockIdx.x * 128, n0 = blockIdx.y * 128;
    const int lane = tid & 63;
    const int wave = tid >> 6;
    const int wr = (wave >> 1) * 64, wc = (wave & 1) * 64;
    const int l15 = lane & 15, l4 = lane >> 4;
    f32x4 acc[4][4] = {};

    const int srow = tid >> 1;
    const int scol = (tid & 1) * 16;

    for (int k0 = 0; k0 < Kp; k0 += 32) {
        {
            const unsigned short* ag = Ahi + (size_t)(m0 + srow) * Kp + k0 + scol;
            *reinterpret_cast<short8v*>(&At_h[srow][scol])     = *reinterpret_cast<const short8v*>(ag);
            *reinterpret_cast<short8v*>(&At_h[srow][scol + 8]) = *reinterpret_cast<const short8v*>(ag + 8);
            const unsigned short* bg = Bthi + (size_t)(n0 + srow) * Kp + k0 + scol;
            *reinterpret_cast<short8v*>(&Bt_h[srow][scol])     = *reinterpret_cast<const short8v*>(bg);
            *reinterpret_cast<short8v*>(&Bt_h[srow][scol + 8]) = *reinterpret_cast<const short8v*>(bg + 8);
            if (PASSES > 1) {
                const unsigned short* ag2 = Alo + (size_t)(m0 + srow) * Kp + k0 + scol;
                *reinterpret_cast<short8v*>(&At_l[srow][scol])     = *reinterpret_cast<const short8v*>(ag2);
                *reinterpret_cast<short8v*>(&At_l[srow][scol + 8]) = *reinterpret_cast<const short8v*>(ag2 + 8);
                const unsigned short* bg2 = Btlo + (size_t)(n0 + srow) * Kp + k0 + scol;
                *reinterpret_cast<short8v*>(&Bt_l[srow][scol])     = *reinterpret_cast<const short8v*>(bg2);
                *reinterpret_cast<short8v*>(&Bt_l[srow][scol + 8]) = *reinterpret_cast<const short8v*>(bg2 + 8);
            }
        }
        __syncthreads();
        short8v a_h[4], b_h[4], a_l[4], b_l[4];
        #pragma unroll
        for (int f = 0; f < 4; ++f) {
            a_h[f] = *reinterpret_cast<const short8v*>(&At_h[wr + f*16 + l15][l4*8]);
            b_h[f] = *reinterpret_cast<const short8v*>(&Bt_h[wc + f*16 + l15][l4*8]);
            if (PASSES > 1) {
                a_l[f] = *reinterpret_cast<const short8v*>(&At_l[wr + f*16 + l15][l4*8]);
                b_l[f] = *reinterpret_cast<const short8v*>(&Bt_l[wc + f*16 + l15][l4*8]);
            }
        }
        #pragma unroll
        for (int i = 0; i < 4; ++i) {
            #pragma unroll
            for (int j = 0; j < 4; ++j) {
                acc[i][j] = __builtin_amdgcn_mfma_f32_16x16x32_bf16(a_h[i], b_h[j], acc[i][j], 0, 0, 0);
                if (PASSES > 1) {
                    acc[i][j] = __builtin_amdgcn_mfma_f32_16x16x32_bf16(a_l[i], b_h[j], acc[i][j], 0, 0, 0);
                    acc[i][j] = __builtin_amdgcn_mfma_f32_16x16x32_bf16(a_h[i], b_l[j], acc[i][j], 0, 0, 0);
                }
            }
        }
        __syncthreads();
    }
    #pragma unroll
    for (int i = 0; i < 4; ++i) {
        #pragma unroll
        for (int j = 0; j < 4; ++j) {
            int col = n0 + wc + j * 16 + l15;
            float badd = BIAS ? bias[col] : 0.f;
            #pragma unroll
            for (int r = 0; r < 4; ++r) {
                int row = m0 + wr + i * 16 + l4 * 4 + r;
                float v = acc[i][j][r] + badd;
                if (RELU) v = fmaxf(v, 0.f);
                C[(size_t)row * N + col] = v;
            }
        }
    }
}

// ---------------- MFMA SW GEMM with fused attention scores ----------------
// Computes SW = SRhi @ Wswt^T in-register, then per fragment emits
// partial_d = sum_j tanh(c + dp[col])*v[col], partial_t with topic row.
// Partials: dscp/tscp [8192][8], slot = blockIdx.y*2 + (wc>>6). No C store.
__global__ __launch_bounds__(256) void mfma_swscore_kernel(
    const unsigned short* __restrict__ Ahi, const unsigned short* __restrict__ Bthi,
    const float* __restrict__ dptp, const float* __restrict__ vatt,
    const int* __restrict__ tidmap,
    float* __restrict__ dscp, float* __restrict__ tscp)
{
    __shared__ unsigned short At_h[128][40];
    __shared__ unsigned short Bt_h[128][40];
    const int tid = threadIdx.x;
    const int m0 = blockIdx.x * 128, n0 = blockIdx.y * 128;
    const int Kp = 256, N = 512;
    (void)N;
    const int lane = tid & 63;
    const int wave = tid >> 6;
    const int wr = (wave >> 1) * 64, wc = (wave & 1) * 64;
    const int l15 = lane & 15, l4 = lane >> 4;
    f32x4 acc[4][4] = {};

    const int srow = tid >> 1;
    const int scol = (tid & 1) * 16;

    for (int k0 = 0; k0 < Kp; k0 += 32) {
        {
            const unsigned short* ag = Ahi + (size_t)(m0 + srow) * Kp + k0 + scol;
            *reinterpret_cast<short8v*>(&At_h[srow][scol])     = *reinterpret_cast<const short8v*>(ag);
            *reinterpret_cast<short8v*>(&At_h[srow][scol + 8]) = *reinterpret_cast<const short8v*>(ag + 8);
            const unsigned short* bg = Bthi + (size_t)(n0 + srow) * Kp + k0 + scol;
            *reinterpret_cast<short8v*>(&Bt_h[srow][scol])     = *reinterpret_cast<const short8v*>(bg);
            *reinterpret_cast<short8v*>(&Bt_h[srow][scol + 8]) = *reinterpret_cast<const short8v*>(bg + 8);
        }
        __syncthreads();
        short8v a_h[4], b_h[4];
        #pragma unroll
        for (int f = 0; f < 4; ++f) {
            a_h[f] = *reinterpret_cast<const short8v*>(&At_h[wr + f*16 + l15][l4*8]);
            b_h[f] = *reinterpret_cast<const short8v*>(&Bt_h[wc + f*16 + l15][l4*8]);
        }
        #pragma unroll
        for (int i = 0; i < 4; ++i)
            #pragma unroll
            for (int j = 0; j < 4; ++j)
                acc[i][j] = __builtin_amdgcn_mfma_f32_16x16x32_bf16(a_h[i], b_h[j], acc[i][j], 0, 0, 0);
        __syncthreads();
    }
    // fused scores epilogue
    const int bb = m0 >> 8;                 // 128-row tile lies in one batch
    const float* dpr = dptp + (size_t)bb * 512;
    float vv[4], dpv[4];
    #pragma unroll
    for (int j = 0; j < 4; ++j) {
        int col = n0 + wc + j * 16 + l15;
        vv[j] = vatt[col];
        dpv[j] = dpr[col];
    }
    const int slot = blockIdx.y * 2 + (wc >> 6);
    #pragma unroll
    for (int i = 0; i < 4; ++i) {
        #pragma unroll
        for (int r = 0; r < 4; ++r) {
            int row = m0 + wr + i * 16 + l4 * 4 + r;
            int ti = tidmap[row];
            const float* tpr = dptp + (size_t)(32 + bb * 16 + ti) * 512;
            float sd = 0.f, st = 0.f;
            #pragma unroll
            for (int j = 0; j < 4; ++j) {
                int col = n0 + wc + j * 16 + l15;
                float c = acc[i][j][r];
                sd += fast_tanh(c + dpv[j]) * vv[j];
                st += fast_tanh(c + tpr[col]) * vv[j];
            }
            sd += __shfl_xor(sd, 1); sd += __shfl_xor(sd, 2);
            sd += __shfl_xor(sd, 4); sd += __shfl_xor(sd, 8);
            st += __shfl_xor(st, 1); st += __shfl_xor(st, 2);
            st += __shfl_xor(st, 4); st += __shfl_xor(st, 8);
            if (l15 == 0) {
                dscp[(size_t)row * 8 + slot] = sd;
                tscp[(size_t)row * 8 + slot] = st;
            }
        }
    }
}

// ---------------- 64x64 fp32 GEMM (dptp only) ----------------
template<bool BIAS, bool RELU>
__global__ __launch_bounds__(256) void gemm_kernel(
    const float* __restrict__ A, const float* __restrict__ B,
    const float* __restrict__ bias, float* __restrict__ C,
    int M, int N, int K)
{
    __shared__ float As[64][68];
    __shared__ float Bs[64][68];
    const int tid = threadIdx.x;
    const int m0 = blockIdx.x * 64;
    const int n0 = blockIdx.y * 64;
    const int tx = tid & 15, ty = tid >> 4;
    const int lr = tid >> 2;
    const int lc = tid & 3;
    float acc[4][4] = {};

    for (int k0 = 0; k0 < K; k0 += 64) {
        #pragma unroll
        for (int i = 0; i < 4; ++i) {
            int kk = lc * 4 + i * 16;
            int gm = m0 + lr;
            int gk = k0 + kk;
            float4 v = {0,0,0,0};
            if (gm < M && gk < K)
                v = *reinterpret_cast<const float4*>(A + (size_t)gm * K + gk);
            As[kk+0][lr] = v.x; As[kk+1][lr] = v.y; As[kk+2][lr] = v.z; As[kk+3][lr] = v.w;
        }
        #pragma unroll
        for (int i = 0; i < 4; ++i) {
            int nn = lc * 4 + i * 16;
            int gk = k0 + lr;
            float4 v = {0,0,0,0};
            if (gk < K)
                v = *reinterpret_cast<const float4*>(B + (size_t)gk * N + n0 + nn);
            *reinterpret_cast<float4*>(&Bs[lr][nn]) = v;
        }
        __syncthreads();
        #pragma unroll 8
        for (int k = 0; k < 64; ++k) {
            float4 av = *reinterpret_cast<const float4*>(&As[k][ty*4]);
            float4 bv = *reinterpret_cast<const float4*>(&Bs[k][tx*4]);
            fma44(av, bv, acc);
        }
        __syncthreads();
    }
    #pragma unroll
    for (int r = 0; r < 4; ++r) {
        int row = m0 + ty * 4 + r;
        if (row < M) {
            float4 v = {acc[r][0], acc[r][1], acc[r][2], acc[r][3]};
            if (BIAS) {
                const float* bp = bias + n0 + tx * 4;
                v.x += bp[0]; v.y += bp[1]; v.z += bp[2]; v.w += bp[3];
            }
            if (RELU) {
                v.x = fmaxf(v.x, 0.f); v.y = fmaxf(v.y, 0.f);
                v.z = fmaxf(v.z, 0.f); v.w = fmaxf(v.w, 0.f);
            }
            *reinterpret_cast<float4*>(C + (size_t)row * N + n0 + tx * 4) = v;
        }
    }
}

// ---------------- GRU scan (r6: single barrier / step) ----------------
__global__ __launch_bounds__(512, 1) void gru_scan_kernel(
    const float* __restrict__ gi,
    const float* __restrict__ Whh_f, const float* __restrict__ Whh_b,
    const float* __restrict__ bhh_f, const float* __restrict__ bhh_b,
    float* __restrict__ sent_rep, float* __restrict__ hT)
{
    const int blk = blockIdx.x;
    const int dir = blk >> 5;
    const int b   = blk & 31;
    const int t = threadIdx.x;
    const int lane = t & 63;
    const int w_id = t >> 6;
    const int q = lane >> 4;
    const int m = lane & 15;
    const int j = w_id * 16 + m;
    const float* Whh = dir ? Whh_b : Whh_f;
    const float* bhh = dir ? bhh_b : bhh_f;
    __shared__ float hbufA[144];
    __shared__ float hbufB[144];

    const float* wr0 = Whh + (size_t)j * 128 + 32 * q;
    const float* wr1 = wr0 + 128 * 128;
    const float* wr2 = wr0 + 256 * 128;
    float4 wA0 = *reinterpret_cast<const float4*>(wr0 +  0);
    float4 wA1 = *reinterpret_cast<const float4*>(wr0 +  4);
    float4 wA2 = *reinterpret_cast<const float4*>(wr0 +  8);
    float4 wA3 = *reinterpret_cast<const float4*>(wr0 + 12);
    float4 wA4 = *reinterpret_cast<const float4*>(wr0 + 16);
    float4 wA5 = *reinterpret_cast<const float4*>(wr0 + 20);
    float4 wA6 = *reinterpret_cast<const float4*>(wr0 + 24);
    float4 wA7 = *reinterpret_cast<const float4*>(wr0 + 28);
    float4 wB0 = *reinterpret_cast<const float4*>(wr1 +  0);
    float4 wB1 = *reinterpret_cast<const float4*>(wr1 +  4);
    float4 wB2 = *reinterpret_cast<const float4*>(wr1 +  8);
    float4 wB3 = *reinterpret_cast<const float4*>(wr1 + 12);
    float4 wB4 = *reinterpret_cast<const float4*>(wr1 + 16);
    float4 wB5 = *reinterpret_cast<const float4*>(wr1 + 20);
    float4 wB6 = *reinterpret_cast<const float4*>(wr1 + 24);
    float4 wB7 = *reinterpret_cast<const float4*>(wr1 + 28);
    float4 wC0 = *reinterpret_cast<const float4*>(wr2 +  0);
    float4 wC1 = *reinterpret_cast<const float4*>(wr2 +  4);
    float4 wC2 = *reinterpret_cast<const float4*>(wr2 +  8);
    float4 wC3 = *reinterpret_cast<const float4*>(wr2 + 12);
    float4 wC4 = *reinterpret_cast<const float4*>(wr2 + 16);
    float4 wC5 = *reinterpret_cast<const float4*>(wr2 + 20);
    float4 wC6 = *reinterpret_cast<const float4*>(wr2 + 24);
    float4 wC7 = *reinterpret_cast<const float4*>(wr2 + 28);
    const float br = bhh[j];
    const float bz = bhh[128 + j];
    const float bn = bhh[256 + j];

    if (t < 144) { hbufA[t] = 0.f; hbufB[t] = 0.f; }

    const int ji = 36 * (j >> 5) + (j & 31);
    const float* gbase = gi + (size_t)(b * Sk) * GI_N + dir * 384 + j;
    float hold = 0.f;
    float gir = 0.f, giz = 0.f, gin_ = 0.f;
    {
        const int s0 = dir ? (Sk - 1) : 0;
        const float* gp = gbase + (size_t)s0 * GI_N;
        gir = gp[0]; giz = gp[128]; gin_ = gp[256];
    }
    __syncthreads();

    #define STEP(RD, WR, SEXPR) { \
        const int s = (SEXPR); \
        const float4* hseg = reinterpret_cast<const float4*>(RD) + 9 * q; \
        float pA = 0.f, pB = 0.f, pC = 0.f; \
        { float4 h4; \
          h4 = hseg[0]; \
          pA=fmaf(wA0.x,h4.x,pA); pA=fmaf(wA0.y,h4.y,pA); pA=fmaf(wA0.z,h4.z,pA); pA=fmaf(wA0.w,h4.w,pA); \
          pB=fmaf(wB0.x,h4.x,pB); pB=fmaf(wB0.y,h4.y,pB); pB=fmaf(wB0.z,h4.z,pB); pB=fmaf(wB0.w,h4.w,pB); \
          pC=fmaf(wC0.x,h4.x,pC); pC=fmaf(wC0.y,h4.y,pC); pC=fmaf(wC0.z,h4.z,pC); pC=fmaf(wC0.w,h4.w,pC); \
          h4 = hseg[1]; \
          pA=fmaf(wA1.x,h4.x,pA); pA=fmaf(wA1.y,h4.y,pA); pA=fmaf(wA1.z,h4.z,pA); pA=fmaf(wA1.w,h4.w,pA); \
          pB=fmaf(wB1.x,h4.x,pB); pB=fmaf(wB1.y,h4.y,pB); pB=fmaf(wB1.z,h4.z,pB); pB=fmaf(wB1.w,h4.w,pB); \
          pC=fmaf(wC1.x,h4.x,pC); pC=fmaf(wC1.y,h4.y,pC); pC=fmaf(wC1.z,h4.z,pC); pC=fmaf(wC1.w,h4.w,pC); \
          h4 = hseg[2]; \
          pA=fmaf(wA2.x,h4.x,pA); pA=fmaf(wA2.y,h4.y,pA); pA=fmaf(wA2.z,h4.z,pA); pA=fmaf(wA2.w,h4.w,pA); \
          pB=fmaf(wB2.x,h4.x,pB); pB=fmaf(wB2.y,h4.y,pB); pB=fmaf(wB2.z,h4.z,pB); pB=fmaf(wB2.w,h4.w,pB); \
          pC=fmaf(wC2.x,h4.x,pC); pC=fmaf(wC2.y,h4.y,pC); pC=fmaf(wC2.z,h4.z,pC); pC=fmaf(wC2.w,h4.w,pC); \
          h4 = hseg[3]; \
          pA=fmaf(wA3.x,h4.x,pA); pA=fmaf(wA3.y,h4.y,pA); pA=fmaf(wA3.z,h4.z,pA); pA=fmaf(wA3.w,h4.w,pA); \
          pB=fmaf(wB3.x,h4.x,pB); pB=fmaf(wB3.y,h4.y,pB); pB=fmaf(wB3.z,h4.z,pB); pB=fmaf(wB3.w,h4.w,pB); \
          pC=fmaf(wC3.x,h4.x,pC); pC=fmaf(wC3.y,h4.y,pC); pC=fmaf(wC3.z,h4.z,pC); pC=fmaf(wC3.w,h4.w,pC); \
          h4 = hseg[4]; \
          pA=fmaf(wA4.x,h4.x,pA); pA=fmaf(wA4.y,h4.y,pA); pA=fmaf(wA4.z,h4.z,pA); pA=fmaf(wA4.w,h4.w,pA); \
          pB=fmaf(wB4.x,h4.x,pB); pB=fmaf(wB4.y,h4.y,pB); pB=fmaf(wB4.z,h4.z,pB); pB=fmaf(wB4.w,h4.w,pB); \
          pC=fmaf(wC4.x,h4.x,pC); pC=fmaf(wC4.y,h4.y,pC); pC=fmaf(wC4.z,h4.z,pC); pC=fmaf(wC4.w,h4.w,pC); \
          h4 = hseg[5]; \
          pA=fmaf(wA5.x,h4.x,pA); pA=fmaf(wA5.y,h4.y,pA); pA=fmaf(wA5.z,h4.z,pA); pA=fmaf(wA5.w,h4.w,pA); \
          pB=fmaf(wB5.x,h4.x,pB); pB=fmaf(wB5.y,h4.y,pB); pB=fmaf(wB5.z,h4.z,pB); pB=fmaf(wB5.w,h4.w,pB); \
          pC=fmaf(wC5.x,h4.x,pC); pC=fmaf(wC5.y,h4.y,pC); pC=fmaf(wC5.z,h4.z,pC); pC=fmaf(wC5.w,h4.w,pC); \
          h4 = hseg[6]; \
          pA=fmaf(wA6.x,h4.x,pA); pA=fmaf(wA6.y,h4.y,pA); pA=fmaf(wA6.z,h4.z,pA); pA=fmaf(wA6.w,h4.w,pA); \
          pB=fmaf(wB6.x,h4.x,pB); pB=fmaf(wB6.y,h4.y,pB); pB=fmaf(wB6.z,h4.z,pB); pB=fmaf(wB6.w,h4.w,pB); \
          pC=fmaf(wC6.x,h4.x,pC); pC=fmaf(wC6.y,h4.y,pC); pC=fmaf(wC6.z,h4.z,pC); pC=fmaf(wC6.w,h4.w,pC); \
          h4 = hseg[7]; \
          pA=fmaf(wA7.x,h4.x,pA); pA=fmaf(wA7.y,h4.y,pA); pA=fmaf(wA7.z,h4.z,pA); pA=fmaf(wA7.w,h4.w,pA); \
          pB=fmaf(wB7.x,h4.x,pB); pB=fmaf(wB7.y,h4.y,pB); pB=fmaf(wB7.z,h4.z,pB); pB=fmaf(wB7.w,h4.w,pB); \
          pC=fmaf(wC7.x,h4.x,pC); pC=fmaf(wC7.y,h4.y,pC); pC=fmaf(wC7.z,h4.z,pC); pC=fmaf(wC7.w,h4.w,pC); } \
        pA += __shfl_xor(pA, 16); pA += __shfl_xor(pA, 32); \
        pB += __shfl_xor(pB, 16); pB += __shfl_xor(pB, 32); \
        pC += __shfl_xor(pC, 16); pC += __shfl_xor(pC, 32); \
        if (q == 0) { \
            float r = fast_sigmoid(gir + pA + br); \
            float z = fast_sigmoid(giz + pB + bz); \
            float n = fast_tanh(gin_ + r * (pC + bn)); \
            hold = (1.f - z) * n + z * hold; \
            (WR)[ji] = hold; \
            sent_rep[(size_t)(b * Sk + s) * 256 + dir * 128 + j] = hold; \
            const int sn = dir ? (s > 0 ? s - 1 : 0) : (s + 1 < Sk ? s + 1 : Sk - 1); \
            const float* gp = gbase + (size_t)sn * GI_N; \
            gir = gp[0]; giz = gp[128]; gin_ = gp[256]; \
        } \
        barrier_lgkm(); \
    }

    for (int step = 0; step < Sk; step += 2) {
        STEP(hbufA, hbufB, dir ? (Sk - 1 - step) : step);
        STEP(hbufB, hbufA, dir ? (Sk - 2 - step) : (step + 1));
    }
    #undef STEP

    if (q == 0) hT[dir * 4096 + b * 128 + j] = hold;
}

// ---------------- prep: doc_vec + topic_mat ----------------
__device__ __forceinline__ float4 sr_load_guard(const float* sr, int b, int sidx, int j4) {
    if (sidx < 0 || sidx >= Sk) { float4 z = {0,0,0,0}; return z; }
    return reinterpret_cast<const float4*>(sr)[(size_t)(b * Sk + sidx) * 64 + j4];
}
__global__ __launch_bounds__(64) void prep_kernel(
    const int* __restrict__ tse, const float* __restrict__ sent_rep,
    const float* __restrict__ hT, float* __restrict__ dvtm)
{
    const int b = blockIdx.x;
    const int t = blockIdx.y;
    const int j4 = threadIdx.x;
    if (t == 16) {
        int dir = b >> 4;
        int bb = 2 * (b & 15) + (j4 >> 5);
        int jj4 = j4 & 31;
        float4 v = reinterpret_cast<const float4*>(hT)[dir * 1024 + bb * 32 + jj4];
        reinterpret_cast<float4*>(dvtm)[b * 64 + j4] = v;
    } else {
        int st = tse[b * 32 + t * 2];
        int en = tse[b * 32 + t * 2 + 1];
        float4 va, vb;
        if (j4 < 32) {
            va = sr_load_guard(sent_rep, b, en - 1, j4);
            vb = sr_load_guard(sent_rep, b, st - 2, j4);
        } else {
            va = sr_load_guard(sent_rep, b, st - 1, j4);
            vb = sr_load_guard(sent_rep, b, en, j4);
        }
        float4 v = {va.x - vb.x, va.y - vb.y, va.z - vb.z, va.w - vb.w};
        reinterpret_cast<float4*>(dvtm)[(32 + b * 16 + t) * 64 + j4] = v;
    }
}

// ---------------- topic map ----------------
__global__ __launch_bounds__(256) void topic_map_kernel(
    const int* __restrict__ tse, int* __restrict__ tidmap)
{
    const int b = blockIdx.x, s = threadIdx.x;
    int ti = 0;
    #pragma unroll
    for (int t = 1; t < 16; ++t) ti += (s >= tse[b * 32 + t * 2] - 1) ? 1 : 0;
    tidmap[b * 256 + s] = ti;
}

// ---------------- softmax (sums partials, outputs weights) ----------------
__global__ __launch_bounds__(256) void softmax_kernel(
    const float* __restrict__ dscp, const float* __restrict__ tscp,
    float* __restrict__ dsc, float* __restrict__ tsc)
{
    const int b = blockIdx.x, sidx = threadIdx.x;
    const int lane = sidx & 63, wid = sidx >> 6;
    __shared__ float rd[4], rt[4];
    const float4* dp8 = reinterpret_cast<const float4*>(dscp + (size_t)(b * Sk + sidx) * 8);
    const float4* tp8 = reinterpret_cast<const float4*>(tscp + (size_t)(b * Sk + sidx) * 8);
    float4 d0 = dp8[0], d1 = dp8[1], t0 = tp8[0], t1 = tp8[1];
    float d = ((d0.x + d0.y) + (d0.z + d0.w)) + ((d1.x + d1.y) + (d1.z + d1.w));
    float t = ((t0.x + t0.y) + (t0.z + t0.w)) + ((t1.x + t1.y) + (t1.z + t1.w));
    float md = d, mt = t;
    #pragma unroll
    for (int off = 32; off; off >>= 1) {
        md = fmaxf(md, __shfl_xor(md, off));
        mt = fmaxf(mt, __shfl_xor(mt, off));
    }
    if (lane == 0) { rd[wid] = md; rt[wid] = mt; }
    __syncthreads();
    md = fmaxf(fmaxf(rd[0], rd[1]), fmaxf(rd[2], rd[3]));
    mt = fmaxf(fmaxf(rt[0], rt[1]), fmaxf(rt[2], rt[3]));
    float ed = __expf(d - md), et = __expf(t - mt);
    float sd = ed, stt = et;
    #pragma unroll
    for (int off = 32; off; off >>= 1) {
        sd += __shfl_xor(sd, off);
        stt += __shfl_xor(stt, off);
    }
    __syncthreads();
    if (lane == 0) { rd[wid] = sd; rt[wid] = stt; }
    __syncthreads();
    sd = rd[0] + rd[1] + rd[2] + rd[3];
    stt = rt[0] + rt[1] + rt[2] + rt[3];
    dsc[b * Sk + sidx] = ed / sd;
    tsc[b * Sk + sidx] = et / stt;
}

// ---------------- build inp (bf16 hi/lo) = [sent_rep, context] ------------
__global__ __launch_bounds__(128) void build_inp_kernel(
    const float* __restrict__ sent_rep, const float* __restrict__ dvtm,
    const float* __restrict__ dw, const float* __restrict__ tw,
    const int* __restrict__ tidmap,
    unsigned short* __restrict__ inpH, unsigned short* __restrict__ inpL)
{
    int row = blockIdx.x;
    int b = row >> 8;
    int f4c = threadIdx.x;
    float4 v;
    if (f4c < 64) {
        v = reinterpret_cast<const float4*>(sent_rep)[(size_t)row * 64 + f4c];
    } else {
        int ti = tidmap[row];
        float dwv = dw[row], twv = tw[row];
        int j4 = f4c - 64;
        float4 dv = reinterpret_cast<const float4*>(dvtm)[b * 64 + j4];
        float4 tm = reinterpret_cast<const float4*>(dvtm)[(32 + b * 16 + ti) * 64 + j4];
        v.x = dwv * dv.x + twv * tm.x;
        v.y = dwv * dv.y + twv * tm.y;
        v.z = dwv * dv.z + twv * tm.z;
        v.w = dwv * dv.w + twv * tm.w;
    }
    ushort4 h, l;
    h.x = f2bf(v.x); h.y = f2bf(v.y); h.z = f2bf(v.z); h.w = f2bf(v.w);
    l.x = f2bf(v.x - bf2f(h.x)); l.y = f2bf(v.y - bf2f(h.y));
    l.z = f2bf(v.z - bf2f(h.z)); l.w = f2bf(v.w - bf2f(h.w));
    *reinterpret_cast<ushort4*>(inpH + (size_t)row * 512 + f4c * 4) = h;
    *reinterpret_cast<ushort4*>(inpL + (size_t)row * 512 + f4c * 4) = l;
}

// ---------------- final logits ----------------
__global__ __launch_bounds__(256) void logits_kernel(
    const float* __restrict__ hdd, const float* __restrict__ W2,
    const float* __restrict__ b2, float* __restrict__ out)
{
    int row = (blockIdx.x << 2) + (threadIdx.x >> 6);
    int lane = threadIdx.x & 63;
    if (row >= NROWS) return;
    float acc = hdd[(size_t)row * 128 + lane] * W2[lane]
              + hdd[(size_t)row * 128 + 64 + lane] * W2[64 + lane];
    #pragma unroll
    for (int off = 32; off; off >>= 1) acc += __shfl_xor(acc, off);
    if (lane == 0) out[row] = acc + b2[0];
}

// ---------------- launch ----------------
extern "C" void kernel_launch(void* const* d_in, const int* in_sizes, int n_in,
                              void* d_out, int out_size, void* d_ws, size_t ws_size,
                              hipStream_t stream)
{
    const int*   wids  = (const int*)d_in[0];
    const int*   tse   = (const int*)d_in[1];
    const float* table = (const float*)d_in[2];
    const float* Wihf  = (const float*)d_in[3];
    const float* Whhf  = (const float*)d_in[4];
    const float* bihf  = (const float*)d_in[5];
    const float* bhhf  = (const float*)d_in[6];
    const float* Wihb  = (const float*)d_in[7];
    const float* Whhb  = (const float*)d_in[8];
    const float* bihb  = (const float*)d_in[9];
    const float* bhhb  = (const float*)d_in[10];
    const float* vatt  = (const float*)d_in[11];
    const float* Watt  = (const float*)d_in[12];
    const float* W1    = (const float*)d_in[13];
    const float* b1    = (const float*)d_in[14];
    const float* W2    = (const float*)d_in[15];
    const float* b2    = (const float*)d_in[16];
    float* ws = (float*)d_ws;
    float* out = (float*)d_out;

    // layout (float units)
    unsigned short* Ahi   = (unsigned short*)(ws + 0);          // 1,310,720 f
    unsigned short* Alo   = (unsigned short*)(ws + 1310720);    // 1,310,720 f
    float* gi             = ws + 2621440;                       // 6,291,456
    float* sent_rep       = ws + 8912896;                       // 2,097,152
    unsigned short* SRhi  = (unsigned short*)(ws + 11010048);   // 1,048,576 f
    float* hT             = ws + 12058624;                      // 8,192
    float* dvtm           = ws + 12066816;                      // 139,264
    float* dptp           = ws + 12206080;                      // 278,528
    float* dsc            = ws + 12484608;                      // 8,192
    float* tsc            = ws + 12492800;                      // 8,192
    unsigned short* BgtH  = (unsigned short*)(ws + 12500992);   // 122,880 f
    unsigned short* BgtL  = (unsigned short*)(ws + 12623872);   // 122,880 f
    float* bias_gi        = ws + 12746752;                      // 768
    unsigned short* Wswt  = (unsigned short*)(ws + 12747520);   // 65,536 f
    unsigned short* W1H   = (unsigned short*)(ws + 12813056);   // 32,768 f
    unsigned short* W1L   = (unsigned short*)(ws + 12845824);   // 32,768 f
    float* dscp           = ws + 12878592;                      // 65,536
    float* tscp           = ws + 12944128;                      // 65,536
    int*   tidmap         = (int*)(ws + 13009664);              // 8,192
    // end 13,017,856 floats
    // dead-zone reuse (Ahi/Alo/gi dead after scan):
    unsigned short* inpH  = (unsigned short*)(ws + 0);          // 2,097,152 f
    unsigned short* inpL  = (unsigned short*)(ws + 2097152);    // 2,097,152 f
    float* hdd            = ws + 4194304;                       // 1,048,576

    if (ws_size < (size_t)13017856 * sizeof(float)) return;

    pack_kernel<<<960, 256, 0, stream>>>(Wihf, Wihb, bihf, bihb, Watt, W1,
                                         BgtH, BgtL, bias_gi, Wswt, W1H, W1L);
    embed_mean_kernel<<<2048, 256, 0, stream>>>(wids, table, Ahi, Alo);
    mfma_gemm_kernel<3, true, false><<<dim3(64, 6), 256, 0, stream>>>(
        Ahi, Alo, BgtH, BgtL, bias_gi, gi, NROWS, 768, KPAD);
    gru_scan_kernel<<<64, 512, 0, stream>>>(gi, Whhf, Whhb, bhhf, bhhb, sent_rep, hT);
    cvt_bf16_kernel<<<1024, 256, 0, stream>>>(sent_rep, SRhi, NROWS * 256 / 8);
    prep_kernel<<<dim3(32, 17), 64, 0, stream>>>(tse, sent_rep, hT, dvtm);
    topic_map_kernel<<<32, 256, 0, stream>>>(tse, tidmap);
    gemm_kernel<false,false><<<dim3(9, 8), 256, 0, stream>>>(dvtm, Watt, nullptr, dptp, 544, 512, 256);
    mfma_swscore_kernel<<<dim3(64, 4), 256, 0, stream>>>(
        SRhi, Wswt, dptp, vatt, tidmap, dscp, tscp);
    softmax_kernel<<<32, 256, 0, stream>>>(dscp, tscp, dsc, tsc);
    build_inp_kernel<<<NROWS, 128, 0, stream>>>(sent_rep, dvtm, dsc, tsc, tidmap, inpH, inpL);
    mfma_gemm_kernel<3, true, true><<<dim3(64, 1), 256, 0, stream>>>(
        inpH, inpL, W1H, W1L, b1, hdd, NROWS, 128, 512);
    logits_kernel<<<2048, 256, 0, stream>>>(hdd, W2, b2, out);
}